// Round 12
// baseline (241.198 us; speedup 1.0000x reference)
//
#include <hip/hip_runtime.h>

typedef __bf16 bf16x8 __attribute__((ext_vector_type(8)));
typedef float  f32x4  __attribute__((ext_vector_type(4)));
union BF8 { unsigned short s[8]; bf16x8 v; };

__device__ __forceinline__ unsigned short f2bf(float x){
  unsigned u = __float_as_uint(x);
  u += 0x7fffu + ((u >> 16) & 1u);      // round-to-nearest-even
  return (unsigned short)(u >> 16);
}
__device__ __forceinline__ unsigned cvt_pk_bf16(float lo, float hi){
  unsigned r;
  asm("v_cvt_pk_bf16_f32 %0, %1, %2" : "=v"(r) : "v"(lo), "v"(hi));
  return r;
}
__device__ __forceinline__ float bf2f(unsigned short s){ return __uint_as_float(((unsigned)s) << 16); }
__device__ __forceinline__ float sigm(float x){ return 1.0f/(1.0f + __expf(-x)); }
__device__ __forceinline__ float tanh_fast(float x){ return 1.0f - 2.0f/(__expf(2.0f*x)+1.0f); }

// ---------------- prep: W -> bf16 pre-swizzled (chunk-of-8 ^ (row&7)) ----------------
__global__ void k_prep(const float* __restrict__ Wihf, const float* __restrict__ Whhf,
                       const float* __restrict__ linw,
                       unsigned short* __restrict__ Wih_sw, unsigned short* __restrict__ Whh_sw,
                       unsigned short* __restrict__ lin_sw)
{
  int tid = blockIdx.x*256 + threadIdx.x;
  if (tid < 49152){
    int row = tid >> 7, col = tid & 127;
    Wih_sw[row*128 + (((col>>3) ^ (row&7))<<3) + (col&7)] = f2bf(Wihf[tid]);
  } else if (tid < 98304){
    int i = tid - 49152; int row = i >> 7, col = i & 127;
    Whh_sw[row*128 + (((col>>3) ^ (row&7))<<3) + (col&7)] = f2bf(Whhf[i]);
  } else if (tid < 114688){
    int i = tid - 98304; int row = i >> 7, col = i & 127;
    lin_sw[row*128 + (((col>>3) ^ (row&7))<<3) + (col&7)] = f2bf(linw[i]);
  }
}

// ---------------- edge index dtype sniff ----------------
__global__ void k_detect(const int* __restrict__ ei, unsigned* __restrict__ flag){
  int v = ei[2*threadIdx.x + 1];
  unsigned long long b = __ballot(v == 0);
  if (threadIdx.x == 0) flag[0] = (b == ~0ULL) ? 1u : 0u;
}

__global__ void k_zero(int* __restrict__ deg, int N){
  int tid = blockIdx.x*256 + threadIdx.x;
  if (tid < N) deg[tid] = 0;
}

__global__ void k_norm(const void* __restrict__ ei, const unsigned* __restrict__ flag,
                       int* __restrict__ src, int* __restrict__ dst, int* __restrict__ deg, int E){
  int e = blockIdx.x*256 + threadIdx.x;
  if (e >= E) return;
  int s, d;
  if (flag[0]){
    const long long* p = (const long long*)ei;
    s = (int)p[e]; d = (int)p[(size_t)E + e];
  } else {
    const int* p = (const int*)ei;
    s = p[e]; d = p[E + e];
  }
  src[e] = s; dst[e] = d;
  atomicAdd(&deg[d], 1);
}

// ---------------- parallel 3-level exclusive scan of deg -> off ----------------
__global__ __launch_bounds__(256) void k_scanA(const int* __restrict__ deg,
    int* __restrict__ off, int* __restrict__ bsum, int N){
  __shared__ int wsum[4];
  const int b = blockIdx.x, t = threadIdx.x;
  const int lane = t & 63, wv = t >> 6;
  const int base = b*1024 + t*4;
  int v[4]; int s = 0;
  #pragma unroll
  for (int j=0;j<4;++j){ v[j] = (base+j < N) ? deg[base+j] : 0; s += v[j]; }
  int inc = s;
  #pragma unroll
  for (int d2=1; d2<64; d2<<=1){ int u = __shfl_up(inc, d2); if (lane >= d2) inc += u; }
  if (lane == 63) wsum[wv] = inc;
  __syncthreads();
  int woff = 0;
  #pragma unroll
  for (int j=0;j<4;++j) if (j < wv) woff += wsum[j];
  int ex = woff + inc - s;
  #pragma unroll
  for (int j=0;j<4;++j){
    if (base+j < N) off[base+j] = ex;
    ex += v[j];
  }
  if (t == 255) bsum[b] = woff + inc;
}

__global__ void k_scanB(int* __restrict__ bsum, int* __restrict__ total, int nB){
  int lane = threadIdx.x;
  int carry = 0;
  for (int base = 0; base < nB; base += 64){
    int i = base + lane;
    int v = (i < nB) ? bsum[i] : 0;
    int inc = v;
    #pragma unroll
    for (int d2=1; d2<64; d2<<=1){ int u = __shfl_up(inc, d2); if (lane >= d2) inc += u; }
    if (i < nB) bsum[i] = carry + inc - v;
    carry += __shfl(inc, 63);
  }
  if (lane == 0) total[0] = carry;
}

__global__ void k_scanC(int* __restrict__ off, const int* __restrict__ bsum,
    const int* __restrict__ total, int* __restrict__ cur, int N){
  int i = blockIdx.x*256 + threadIdx.x;
  if (i < N){ off[i] += bsum[i>>10]; cur[i] = 0; }
  if (i == 0) off[N] = total[0];
}

__global__ void k_scatter(const int* __restrict__ src, const int* __restrict__ dst,
                          const int* __restrict__ off, int* __restrict__ cur,
                          int* __restrict__ eid, int E){
  int e = blockIdx.x*256 + threadIdx.x;
  if (e >= E) return;
  int d = dst[e];
  int p = off[d] + atomicAdd(&cur[d], 1);
  eid[p] = src[e];
}

// ---------------- fused GRU: weights in registers, channel-split, TWO tiles/block -----
// Round-7 measured schedule (runtime pair loop, staging mid-step), widened to 2 tiles:
// each wave runs two independent MFMA/gate chains between the same barriers.
__global__ __launch_bounds__(512, 2) void k_gru_fused(
    const unsigned short* __restrict__ Wih_sw, const unsigned short* __restrict__ Whh_sw,
    const float* __restrict__ bih, const float* __restrict__ bhh,
    const float* __restrict__ seq, float* __restrict__ hout, int nT, int N)
{
  __shared__ unsigned short xbuf[2][2][4096];   // [slot][tile][node*256 + s*128 + swz]
  __shared__ unsigned short hbuf[2][2][2048];   // [buf][tile][node*128 + swz]
  const int tid  = threadIdx.x;
  const int lane = tid & 63, w = tid >> 6;      // w = channel chunk 0..7
  const int col4 = lane & 15, grp = lane >> 4;
  const int tile0 = blockIdx.x*2;
  int t1i = tile0 + 1; if (t1i >= nT) t1i = tile0;
  const int tile1 = t1i;
  const int ch   = 16*w + col4;

  bf16x8 Wf[6][4];
  #pragma unroll
  for (int s6=0; s6<6; ++s6){
    const unsigned short* Wp = (s6 < 3) ? Wih_sw : Whh_sw;
    int row = (s6 % 3)*128 + ch;
    #pragma unroll
    for (int kt=0; kt<4; ++kt)
      Wf[s6][kt] = *(const bf16x8*)(Wp + row*128 + (((kt*4+grp) ^ (row&7))<<3));
  }
  const float brz_r = bih[ch]       + bhh[ch];
  const float brz_z = bih[128 + ch] + bhh[128 + ch];
  const float b_xn  = bih[256 + ch];
  const float b_hn  = bhh[256 + ch];

  float hreg0[4] = {0.f,0.f,0.f,0.f}, hreg1[4] = {0.f,0.f,0.f,0.f};

  f32x4 sv0[2], sv1[2];
  auto stageIssue = [&](int p){               // load pair p (steps 2p,2p+1), both tiles
    #pragma unroll
    for (int rr=0; rr<2; ++rr){
      int nr0 = tile0*16 + 2*w + rr; if (nr0 >= N) nr0 = N-1;
      int nr1 = tile1*16 + 2*w + rr; if (nr1 >= N) nr1 = N-1;
      sv0[rr] = *(const f32x4*)(seq + ((size_t)nr0*16 + 2*p)*128 + lane*4);
      sv1[rr] = *(const f32x4*)(seq + ((size_t)nr1*16 + 2*p)*128 + lane*4);
    }
  };
  auto stageWrite = [&](int p){
    const int s  = lane >> 5;
    const int c0 = (lane & 31) * 4;
    #pragma unroll
    for (int rr=0; rr<2; ++rr){
      int node = 2*w + rr;
      int chunk = (c0 >> 3) ^ node;
      int boff = node*256 + s*128 + chunk*8 + (c0 & 7);
      uint2 pk;
      pk.x = cvt_pk_bf16(sv0[rr][0], sv0[rr][1]);
      pk.y = cvt_pk_bf16(sv0[rr][2], sv0[rr][3]);
      *(uint2*)(&xbuf[p & 1][0][boff]) = pk;
      pk.x = cvt_pk_bf16(sv1[rr][0], sv1[rr][1]);
      pk.y = cvt_pk_bf16(sv1[rr][2], sv1[rr][3]);
      *(uint2*)(&xbuf[p & 1][1][boff]) = pk;
    }
  };
  auto staging = [&](int t){                  // call at even t only
    int pw = t/2 + 1;
    if (pw <= 7) stageWrite(pw);
    int pi = t/2 + 2;
    if (pi <= 7) stageIssue(pi);
  };

  // x-part: acc = bias + x(t) @ Wih
  auto xPart = [&](int t, int tl, f32x4& nr, f32x4& nz, f32x4& nn){
    bf16x8 xa[4];
    const unsigned short* xb = xbuf[(t>>1)&1][tl] + col4*256 + (t&1)*128;
    #pragma unroll
    for (int kt=0;kt<4;++kt){
      int chunk = (kt*4+grp) ^ col4;
      xa[kt] = *(const bf16x8*)(xb + chunk*8);
    }
    nr = (f32x4){brz_r, brz_r, brz_r, brz_r};
    nz = (f32x4){brz_z, brz_z, brz_z, brz_z};
    nn = (f32x4){b_xn,  b_xn,  b_xn,  b_xn };
    #pragma unroll
    for (int kt=0; kt<4; ++kt){
      nr = __builtin_amdgcn_mfma_f32_16x16x32_bf16(xa[kt], Wf[0][kt], nr, 0,0,0);
      nz = __builtin_amdgcn_mfma_f32_16x16x32_bf16(xa[kt], Wf[1][kt], nz, 0,0,0);
      nn = __builtin_amdgcn_mfma_f32_16x16x32_bf16(xa[kt], Wf[2][kt], nn, 0,0,0);
    }
  };
  // h-part: cr,cz += h(t-1)@Whh ; chn = b_hn + h(t-1)@Whh_n
  auto hPart = [&](int t, int tl, f32x4& cr, f32x4& cz, f32x4& chn){
    bf16x8 ha[4];
    const unsigned short* hb = hbuf[t&1][tl];
    #pragma unroll
    for (int kt=0;kt<4;++kt){
      int chunk = (kt*4+grp) ^ col4;
      ha[kt] = *(const bf16x8*)(hb + col4*128 + chunk*8);
    }
    chn = (f32x4){b_hn, b_hn, b_hn, b_hn};
    #pragma unroll
    for (int kt=0; kt<4; ++kt){
      cr  = __builtin_amdgcn_mfma_f32_16x16x32_bf16(ha[kt], Wf[3][kt], cr , 0,0,0);
      cz  = __builtin_amdgcn_mfma_f32_16x16x32_bf16(ha[kt], Wf[4][kt], cz , 0,0,0);
      chn = __builtin_amdgcn_mfma_f32_16x16x32_bf16(ha[kt], Wf[5][kt], chn, 0,0,0);
    }
  };
  auto gates = [&](int t, int tl, float* hr,
                   const f32x4& cr, const f32x4& cz, const f32x4& cn, const f32x4& chn){
    unsigned short* hbw = hbuf[(t+1)&1][tl];
    #pragma unroll
    for (int q=0; q<4; q+=2){
      float r0 = sigm(cr[q]),   z0 = sigm(cz[q]);
      float n0 = tanh_fast(cn[q]   + r0*chn[q]);
      float h0 = n0 + z0*(hr[q]   - n0); hr[q]   = h0;
      float r1 = sigm(cr[q+1]), z1 = sigm(cz[q+1]);
      float n1 = tanh_fast(cn[q+1] + r1*chn[q+1]);
      float h1 = n1 + z1*(hr[q+1] - n1); hr[q+1] = h1;
      if (t < 15){
        unsigned pk = cvt_pk_bf16(h0, h1);
        int nd0 = grp*4 + q, nd1 = nd0 + 1;
        int c0 = ((ch>>3) ^ nd0), c1 = ((ch>>3) ^ nd1);
        hbw[nd0*128 + c0*8 + (ch&7)] = (unsigned short)pk;
        hbw[nd1*128 + c1*8 + (ch&7)] = (unsigned short)(pk >> 16);
      }
    }
  };

  // ---- prologue: pairs 0,1 staged; step 0 computed (h(-1)=0) ----
  stageIssue(0); stageWrite(0);
  stageIssue(1);
  __syncthreads();

  f32x4 A0r,A0z,A0n, A1r,A1z,A1n, B0r,B0z,B0n, B1r,B1z,B1n, Hn0, Hn1;
  xPart(0,0,A0r,A0z,A0n); xPart(0,1,A1r,A1z,A1n);
  Hn0 = (f32x4){b_hn,b_hn,b_hn,b_hn}; Hn1 = Hn0;   // h(-1) = 0
  gates(0,0,hreg0,A0r,A0z,A0n,Hn0); gates(0,1,hreg1,A1r,A1z,A1n,Hn1);
  staging(0);
  xPart(1,0,B0r,B0z,B0n); xPart(1,1,B1r,B1z,B1n);

  for (int tp = 0; tp < 7; ++tp){
    const int t1 = 2*tp + 1, t2 = 2*tp + 2;
    __syncthreads();
    hPart(t1,0,B0r,B0z,Hn0); hPart(t1,1,B1r,B1z,Hn1);
    gates(t1,0,hreg0,B0r,B0z,B0n,Hn0); gates(t1,1,hreg1,B1r,B1z,B1n,Hn1);
    xPart(t2,0,A0r,A0z,A0n); xPart(t2,1,A1r,A1z,A1n);
    __syncthreads();
    hPart(t2,0,A0r,A0z,Hn0); hPart(t2,1,A1r,A1z,Hn1);
    gates(t2,0,hreg0,A0r,A0z,A0n,Hn0); gates(t2,1,hreg1,A1r,A1z,A1n,Hn1);
    staging(t2);
    xPart(t2+1,0,B0r,B0z,B0n); xPart(t2+1,1,B1r,B1z,B1n);
  }
  __syncthreads();
  hPart(15,0,B0r,B0z,Hn0); hPart(15,1,B1r,B1z,Hn1);
  gates(15,0,hreg0,B0r,B0z,B0n,Hn0); gates(15,1,hreg1,B1r,B1z,B1n,Hn1);

  #pragma unroll
  for (int q=0; q<4; ++q){
    int n0 = tile0*16 + grp*4 + q;
    if (n0 < N) hout[(size_t)n0*128 + ch] = hreg0[q];
    int n1 = tile1*16 + grp*4 + q;
    if (tile1 != tile0 && n1 < N) hout[(size_t)n1*128 + ch] = hreg1[q];
  }
}

// ---------------- GAT linear (MFMA) + fused attention scalars; x stored bf16 ----------------
__global__ __launch_bounds__(256) void k_gat1(
    const float* __restrict__ hsrc, const unsigned short* __restrict__ lin_sw,
    const float* __restrict__ att_s, const float* __restrict__ att_d,
    unsigned short* __restrict__ xbf, float* __restrict__ a_s, float* __restrict__ a_d,
    int N, int nT)
{
  __shared__ unsigned short Llds[16384];
  const int tid = threadIdx.x;
  for (int i = tid; i < 2048; i += 256)
    ((uint4*)Llds)[i] = ((const uint4*)lin_sw)[i];
  __syncthreads();
  const int lane = tid & 63, wloc = tid >> 6;
  const int col4 = lane & 15, grp = lane >> 4;
  const int tile = blockIdx.x*4 + wloc;
  if (tile >= nT) return;
  float ats[8], atd[8];
  #pragma unroll
  for (int ct=0;ct<8;++ct){ ats[ct] = att_s[ct*16+col4]; atd[ct] = att_d[ct*16+col4]; }
  int nrow = tile*16 + col4; if (nrow >= N) nrow = N-1;
  const float* xr = hsrc + (size_t)nrow*128 + grp*8;
  bf16x8 xa[4];
  #pragma unroll
  for (int kt=0;kt<4;++kt){
    f32x4 lo = *(const f32x4*)(xr + kt*32);
    f32x4 hi = *(const f32x4*)(xr + kt*32 + 4);
    BF8 u;
    #pragma unroll
    for (int j=0;j<4;++j){ u.s[j]=f2bf(lo[j]); u.s[4+j]=f2bf(hi[j]); }
    xa[kt] = u.v;
  }
  f32x4 acc[8];
  #pragma unroll
  for (int ct=0;ct<8;++ct) acc[ct] = (f32x4)0.0f;
  #pragma unroll
  for (int kt=0;kt<4;++kt){
    #pragma unroll
    for (int ct=0;ct<8;++ct){
      int row = ct*16+col4;
      const bf16x8 b = *(const bf16x8*)(Llds + row*128 + (((kt*4+grp)^(row&7))<<3));
      acc[ct] = __builtin_amdgcn_mfma_f32_16x16x32_bf16(xa[kt], b, acc[ct], 0,0,0);
    }
  }
  float ss[4] = {0,0,0,0}, dd[4] = {0,0,0,0};
  #pragma unroll
  for (int ct=0;ct<8;++ct)
    #pragma unroll
    for (int q=0;q<4;++q){
      float xv = acc[ct][q];
      int n = tile*16 + grp*4 + q;
      if (n < N) xbf[(size_t)n*128 + ct*16 + col4] = f2bf(xv);
      ss[q] += xv * ats[ct];
      dd[q] += xv * atd[ct];
    }
  #pragma unroll
  for (int m=1; m<16; m<<=1){
    #pragma unroll
    for (int q=0;q<4;++q){
      ss[q] += __shfl_xor(ss[q], m);
      dd[q] += __shfl_xor(dd[q], m);
    }
  }
  if (col4 == 0){
    #pragma unroll
    for (int q=0;q<4;++q){
      int n = tile*16 + grp*4 + q;
      if (n < N){ a_s[n] = ss[q]; a_d[n] = dd[q]; }
    }
  }
}

// ---------------- CSR aggregation: one wave per destination node, 4x unrolled ----------------
__global__ __launch_bounds__(256) void k_agg2(
    const int* __restrict__ off, const int* __restrict__ eid,
    const float* __restrict__ a_s, const float* __restrict__ a_d,
    const unsigned short* __restrict__ xbf, const float* __restrict__ bias,
    float* __restrict__ out2, int N)
{
  int d = blockIdx.x*4 + (threadIdx.x >> 6);
  if (d >= N) return;
  const int lane = threadIdx.x & 63;
  const unsigned* xw = (const unsigned*)xbf;   // 2 bf16 channels per uint
  const float ad_d = a_d[d];
  float a0 = a_s[d] + ad_d; a0 = a0 > 0.f ? a0 : 0.2f*a0;
  float w = __expf(a0);
  unsigned pv = xw[(size_t)d*64 + lane];
  float den  = w;
  float acc0 = w * bf2f((unsigned short)(pv & 0xffffu));
  float acc1 = w * bf2f((unsigned short)(pv >> 16));
  int i = off[d];
  const int i1 = off[d+1];
  for (; i + 3 < i1; i += 4){
    int s0 = eid[i], s1 = eid[i+1], s2 = eid[i+2], s3 = eid[i+3];
    unsigned p0 = xw[(size_t)s0*64 + lane];
    unsigned p1 = xw[(size_t)s1*64 + lane];
    unsigned p2 = xw[(size_t)s2*64 + lane];
    unsigned p3 = xw[(size_t)s3*64 + lane];
    float b0 = a_s[s0] + ad_d, b1 = a_s[s1] + ad_d, b2 = a_s[s2] + ad_d, b3 = a_s[s3] + ad_d;
    b0 = b0 > 0.f ? b0 : 0.2f*b0;  b1 = b1 > 0.f ? b1 : 0.2f*b1;
    b2 = b2 > 0.f ? b2 : 0.2f*b2;  b3 = b3 > 0.f ? b3 : 0.2f*b3;
    float w0 = __expf(b0), w1 = __expf(b1), w2 = __expf(b2), w3 = __expf(b3);
    den += w0 + w1 + w2 + w3;
    acc0 += w0 * bf2f((unsigned short)(p0 & 0xffffu)) + w1 * bf2f((unsigned short)(p1 & 0xffffu))
          + w2 * bf2f((unsigned short)(p2 & 0xffffu)) + w3 * bf2f((unsigned short)(p3 & 0xffffu));
    acc1 += w0 * bf2f((unsigned short)(p0 >> 16)) + w1 * bf2f((unsigned short)(p1 >> 16))
          + w2 * bf2f((unsigned short)(p2 >> 16)) + w3 * bf2f((unsigned short)(p3 >> 16));
  }
  for (; i < i1; ++i){
    int s = eid[i];
    float a = a_s[s] + ad_d; a = a > 0.f ? a : 0.2f*a;
    float ww = __expf(a);
    unsigned pp = xw[(size_t)s*64 + lane];
    den  += ww;
    acc0 += ww * bf2f((unsigned short)(pp & 0xffffu));
    acc1 += ww * bf2f((unsigned short)(pp >> 16));
  }
  float inv = 1.0f/den;
  float2 o;
  o.x = acc0*inv + bias[2*lane];
  o.y = acc1*inv + bias[2*lane+1];
  *(float2*)(out2 + (size_t)d*128 + 2*lane) = o;
}

extern "C" void kernel_launch(void* const* d_in, const int* in_sizes, int n_in,
                              void* d_out, int out_size, void* d_ws, size_t ws_size,
                              hipStream_t stream)
{
  const float* seq  = (const float*)d_in[0];
  const void*  ei   = d_in[1];
  const float* Wihf = (const float*)d_in[2];
  const float* Whhf = (const float*)d_in[3];
  const float* bih  = (const float*)d_in[4];
  const float* bhh  = (const float*)d_in[5];
  const float* linw = (const float*)d_in[6];
  const float* atts = (const float*)d_in[7];
  const float* attd = (const float*)d_in[8];
  const float* gbias= (const float*)d_in[9];

  const int N  = in_sizes[0] / (16*128);
  const int E  = in_sizes[1] / 2;
  const int nT = (N + 15) / 16;
  const int nB = (N + 1023) / 1024;

  char* ws = (char*)d_ws;
  size_t off_b = 0;
  auto alloc = [&](size_t bytes) -> char* {
    char* p = ws + off_b;
    off_b = (off_b + bytes + 255) & ~(size_t)255;
    return p;
  };
  unsigned short* Wih_sw = (unsigned short*)alloc(98304);
  unsigned short* Whh_sw = (unsigned short*)alloc(98304);
  unsigned short* lin_sw = (unsigned short*)alloc(32768);
  unsigned short* xbf    = (unsigned short*)alloc((size_t)N*128*2);
  float*    a_s    = (float*)   alloc((size_t)N*4);
  float*    a_d    = (float*)   alloc((size_t)N*4);
  unsigned* flag   = (unsigned*)alloc(64);
  int*      srcA   = (int*)     alloc((size_t)E*4);
  int*      dstA   = (int*)     alloc((size_t)E*4);
  int*      deg    = (int*)     alloc((size_t)N*4);
  int*      offs   = (int*)     alloc((size_t)(N+1)*4);
  int*      cur    = (int*)     alloc((size_t)N*4);
  int*      eid    = (int*)     alloc((size_t)E*4);
  int*      bsum   = (int*)     alloc((size_t)(nB+1)*4);
  int*      total  = (int*)     alloc(64);

  float* hout = (float*)d_out;
  float* out2 = hout + (size_t)N*128;

  k_prep   <<<448, 256, 0, stream>>>(Wihf, Whhf, linw, Wih_sw, Whh_sw, lin_sw);
  k_detect <<<1, 64, 0, stream>>>((const int*)ei, flag);
  k_zero   <<<(N + 255)/256, 256, 0, stream>>>(deg, N);
  k_norm   <<<(E + 255)/256, 256, 0, stream>>>(ei, flag, srcA, dstA, deg, E);
  k_scanA  <<<nB, 256, 0, stream>>>(deg, offs, bsum, N);
  k_scanB  <<<1, 64, 0, stream>>>(bsum, total, nB);
  k_scanC  <<<(N + 255)/256, 256, 0, stream>>>(offs, bsum, total, cur, N);
  k_scatter<<<(E + 255)/256, 256, 0, stream>>>(srcA, dstA, offs, cur, eid, E);

  k_gru_fused<<<(nT + 1)/2, 512, 0, stream>>>(Wih_sw, Whh_sw, bih, bhh, seq, hout, nT, N);

  k_gat1<<<(nT + 3)/4, 256, 0, stream>>>(hout, lin_sw, atts, attd, xbf, a_s, a_d, N, nT);
  k_agg2<<<(N + 3)/4, 256, 0, stream>>>(offs, eid, a_s, a_d, xbf, gbias, out2, N);
}

// Round 13
// 229.212 us; speedup vs baseline: 1.0523x; 1.0523x over previous
//
#include <hip/hip_runtime.h>

typedef __bf16 bf16x8 __attribute__((ext_vector_type(8)));
typedef float  f32x4  __attribute__((ext_vector_type(4)));
union BF8 { unsigned short s[8]; bf16x8 v; };

// LDS-only barrier: does NOT drain vmcnt, so in-flight global staging loads
// survive the barrier (the __syncthreads() vmcnt(0) drain was the per-step stall).
// Safe here: the only cross-wave shared state is LDS (hbuf/xbuf), ordered by lgkmcnt(0);
// staging loads land in wave-private VGPRs (no cross-wave hazard).
#define GRU_BARRIER() asm volatile("s_waitcnt lgkmcnt(0)\n\ts_barrier" ::: "memory")

__device__ __forceinline__ unsigned short f2bf(float x){
  unsigned u = __float_as_uint(x);
  u += 0x7fffu + ((u >> 16) & 1u);      // round-to-nearest-even
  return (unsigned short)(u >> 16);
}
__device__ __forceinline__ unsigned cvt_pk_bf16(float lo, float hi){
  unsigned r;
  asm("v_cvt_pk_bf16_f32 %0, %1, %2" : "=v"(r) : "v"(lo), "v"(hi));
  return r;
}
__device__ __forceinline__ float bf2f(unsigned short s){ return __uint_as_float(((unsigned)s) << 16); }
__device__ __forceinline__ float sigm(float x){ return 1.0f/(1.0f + __expf(-x)); }
__device__ __forceinline__ float tanh_fast(float x){ return 1.0f - 2.0f/(__expf(2.0f*x)+1.0f); }

// ---------------- prep: W -> bf16 pre-swizzled (chunk-of-8 ^ (row&7)) ----------------
__global__ void k_prep(const float* __restrict__ Wihf, const float* __restrict__ Whhf,
                       const float* __restrict__ linw,
                       unsigned short* __restrict__ Wih_sw, unsigned short* __restrict__ Whh_sw,
                       unsigned short* __restrict__ lin_sw)
{
  int tid = blockIdx.x*256 + threadIdx.x;
  if (tid < 49152){
    int row = tid >> 7, col = tid & 127;
    Wih_sw[row*128 + (((col>>3) ^ (row&7))<<3) + (col&7)] = f2bf(Wihf[tid]);
  } else if (tid < 98304){
    int i = tid - 49152; int row = i >> 7, col = i & 127;
    Whh_sw[row*128 + (((col>>3) ^ (row&7))<<3) + (col&7)] = f2bf(Whhf[i]);
  } else if (tid < 114688){
    int i = tid - 98304; int row = i >> 7, col = i & 127;
    lin_sw[row*128 + (((col>>3) ^ (row&7))<<3) + (col&7)] = f2bf(linw[i]);
  }
}

// ---------------- edge dtype sniff + deg zero (merged) ----------------
__global__ void k_detzero(const int* __restrict__ ei, unsigned* __restrict__ flag,
                          int* __restrict__ deg, int N){
  int tid = blockIdx.x*256 + threadIdx.x;
  if (tid < N) deg[tid] = 0;
  if (blockIdx.x == 0 && threadIdx.x < 64){
    int v = ei[2*threadIdx.x + 1];
    unsigned long long b = __ballot(v == 0);
    if (threadIdx.x == 0) flag[0] = (b == ~0ULL) ? 1u : 0u;
  }
}

__global__ void k_norm(const void* __restrict__ ei, const unsigned* __restrict__ flag,
                       int* __restrict__ src, int* __restrict__ dst, int* __restrict__ deg, int E){
  int e = blockIdx.x*256 + threadIdx.x;
  if (e >= E) return;
  int s, d;
  if (flag[0]){
    const long long* p = (const long long*)ei;
    s = (int)p[e]; d = (int)p[(size_t)E + e];
  } else {
    const int* p = (const int*)ei;
    s = p[e]; d = p[E + e];
  }
  src[e] = s; dst[e] = d;
  atomicAdd(&deg[d], 1);
}

// ---------------- parallel 3-level exclusive scan of deg -> off ----------------
__global__ __launch_bounds__(256) void k_scanA(const int* __restrict__ deg,
    int* __restrict__ off, int* __restrict__ bsum, int N){
  __shared__ int wsum[4];
  const int b = blockIdx.x, t = threadIdx.x;
  const int lane = t & 63, wv = t >> 6;
  const int base = b*1024 + t*4;
  int v[4]; int s = 0;
  #pragma unroll
  for (int j=0;j<4;++j){ v[j] = (base+j < N) ? deg[base+j] : 0; s += v[j]; }
  int inc = s;
  #pragma unroll
  for (int d2=1; d2<64; d2<<=1){ int u = __shfl_up(inc, d2); if (lane >= d2) inc += u; }
  if (lane == 63) wsum[wv] = inc;
  __syncthreads();
  int woff = 0;
  #pragma unroll
  for (int j=0;j<4;++j) if (j < wv) woff += wsum[j];
  int ex = woff + inc - s;
  #pragma unroll
  for (int j=0;j<4;++j){
    if (base+j < N) off[base+j] = ex;
    ex += v[j];
  }
  if (t == 255) bsum[b] = woff + inc;
}

__global__ void k_scanB(int* __restrict__ bsum, int* __restrict__ total, int nB){
  int lane = threadIdx.x;
  int carry = 0;
  for (int base = 0; base < nB; base += 64){
    int i = base + lane;
    int v = (i < nB) ? bsum[i] : 0;
    int inc = v;
    #pragma unroll
    for (int d2=1; d2<64; d2<<=1){ int u = __shfl_up(inc, d2); if (lane >= d2) inc += u; }
    if (i < nB) bsum[i] = carry + inc - v;
    carry += __shfl(inc, 63);
  }
  if (lane == 0) total[0] = carry;
}

__global__ void k_scanC(int* __restrict__ off, const int* __restrict__ bsum,
    const int* __restrict__ total, int* __restrict__ cur, int N){
  int i = blockIdx.x*256 + threadIdx.x;
  if (i < N){ off[i] += bsum[i>>10]; cur[i] = 0; }
  if (i == 0) off[N] = total[0];
}

__global__ void k_scatter(const int* __restrict__ src, const int* __restrict__ dst,
                          const int* __restrict__ off, int* __restrict__ cur,
                          int* __restrict__ eid, int E){
  int e = blockIdx.x*256 + threadIdx.x;
  if (e >= E) return;
  int d = dst[e];
  int p = off[d] + atomicAdd(&cur[d], 1);
  eid[p] = src[e];
}

// ---------------- fused GRU: weights in registers, channel-split -----
// r7 measured schedule, with LDS-only barriers (no vmcnt drain) and staging
// moved to right-after-barrier-A: stageWrite(tp+2) consumes loads issued a full
// iteration earlier; stageIssue(tp+3) flies across ~2 steps before consumption.
// WAR audit: pair p is read ONLY in iteration p-1 (both xParts); slot (p&1)'s
// previous pair p-2 was last read in iteration p-3; barrier A separates.
__global__ __launch_bounds__(512, 2) void k_gru_fused(
    const unsigned short* __restrict__ Wih_sw, const unsigned short* __restrict__ Whh_sw,
    const float* __restrict__ bih, const float* __restrict__ bhh,
    const float* __restrict__ seq, float* __restrict__ hout, int nT, int N)
{
  __shared__ unsigned short xbuf[2][16*256];   // [slot][node][s(2 steps)][ch swz]
  __shared__ unsigned short hbuf[2][16*128];   // [buf][node][ch swz]
  const int tid  = threadIdx.x;
  const int lane = tid & 63, w = tid >> 6;     // w = channel chunk 0..7
  const int col4 = lane & 15, grp = lane >> 4;
  const int tile = blockIdx.x;
  const int ch   = 16*w + col4;                // this lane's output channel

  bf16x8 Wf[6][4];
  #pragma unroll
  for (int s6=0; s6<6; ++s6){
    const unsigned short* Wp = (s6 < 3) ? Wih_sw : Whh_sw;
    int row = (s6 % 3)*128 + ch;
    #pragma unroll
    for (int kt=0; kt<4; ++kt)
      Wf[s6][kt] = *(const bf16x8*)(Wp + row*128 + (((kt*4+grp) ^ (row&7))<<3));
  }
  const float brz_r = bih[ch]       + bhh[ch];
  const float brz_z = bih[128 + ch] + bhh[128 + ch];
  const float b_xn  = bih[256 + ch];
  const float b_hn  = bhh[256 + ch];

  float hreg[4] = {0.f, 0.f, 0.f, 0.f};

  f32x4 sv[2];
  auto stageIssue = [&](int p){               // load pair p (steps 2p,2p+1)
    #pragma unroll
    for (int rr=0; rr<2; ++rr){
      int nrow = tile*16 + 2*w + rr; if (nrow >= N) nrow = N-1;
      sv[rr] = *(const f32x4*)(seq + ((size_t)nrow*16 + 2*p)*128 + lane*4);
    }
  };
  auto stageWrite = [&](int p){
    const int s  = lane >> 5;
    const int c0 = (lane & 31) * 4;
    #pragma unroll
    for (int rr=0; rr<2; ++rr){
      int node = 2*w + rr;
      int chunk = (c0 >> 3) ^ node;
      uint2 pk;
      pk.x = cvt_pk_bf16(sv[rr][0], sv[rr][1]);
      pk.y = cvt_pk_bf16(sv[rr][2], sv[rr][3]);
      *(uint2*)(&xbuf[p & 1][node*256 + s*128 + chunk*8 + (c0 & 7)]) = pk;
    }
  };

  // x-part: acc = bias + x(t) @ Wih
  auto xPart = [&](int t, f32x4& nr, f32x4& nz, f32x4& nn){
    bf16x8 xa[4];
    const unsigned short* xb = xbuf[(t>>1)&1] + col4*256 + (t&1)*128;
    #pragma unroll
    for (int kt=0;kt<4;++kt){
      int chunk = (kt*4+grp) ^ col4;
      xa[kt] = *(const bf16x8*)(xb + chunk*8);
    }
    nr = (f32x4){brz_r, brz_r, brz_r, brz_r};
    nz = (f32x4){brz_z, brz_z, brz_z, brz_z};
    nn = (f32x4){b_xn,  b_xn,  b_xn,  b_xn };
    #pragma unroll
    for (int kt=0; kt<4; ++kt){
      nr = __builtin_amdgcn_mfma_f32_16x16x32_bf16(xa[kt], Wf[0][kt], nr, 0,0,0);
      nz = __builtin_amdgcn_mfma_f32_16x16x32_bf16(xa[kt], Wf[1][kt], nz, 0,0,0);
      nn = __builtin_amdgcn_mfma_f32_16x16x32_bf16(xa[kt], Wf[2][kt], nn, 0,0,0);
    }
  };
  // h-part: cr,cz += h(t-1)@Whh ; chn = b_hn + h(t-1)@Whh_n
  auto hPart = [&](int t, f32x4& cr, f32x4& cz, f32x4& chn){
    bf16x8 ha[4];
    const unsigned short* hb = hbuf[t&1];
    #pragma unroll
    for (int kt=0;kt<4;++kt){
      int chunk = (kt*4+grp) ^ col4;
      ha[kt] = *(const bf16x8*)(hb + col4*128 + chunk*8);
    }
    chn = (f32x4){b_hn, b_hn, b_hn, b_hn};
    #pragma unroll
    for (int kt=0; kt<4; ++kt){
      cr  = __builtin_amdgcn_mfma_f32_16x16x32_bf16(ha[kt], Wf[3][kt], cr , 0,0,0);
      cz  = __builtin_amdgcn_mfma_f32_16x16x32_bf16(ha[kt], Wf[4][kt], cz , 0,0,0);
      chn = __builtin_amdgcn_mfma_f32_16x16x32_bf16(ha[kt], Wf[5][kt], chn, 0,0,0);
    }
  };
  auto gates = [&](int t, const f32x4& cr, const f32x4& cz, const f32x4& cn, const f32x4& chn){
    unsigned short* hbw = hbuf[(t+1)&1];
    #pragma unroll
    for (int q=0; q<4; q+=2){
      float r0 = sigm(cr[q]),   z0 = sigm(cz[q]);
      float n0 = tanh_fast(cn[q]   + r0*chn[q]);
      float h0 = n0 + z0*(hreg[q]   - n0); hreg[q]   = h0;
      float r1 = sigm(cr[q+1]), z1 = sigm(cz[q+1]);
      float n1 = tanh_fast(cn[q+1] + r1*chn[q+1]);
      float h1 = n1 + z1*(hreg[q+1] - n1); hreg[q+1] = h1;
      if (t < 15){
        unsigned pk = cvt_pk_bf16(h0, h1);
        int nd0 = grp*4 + q, nd1 = nd0 + 1;
        int c0 = ((ch>>3) ^ nd0), c1 = ((ch>>3) ^ nd1);
        hbw[nd0*128 + c0*8 + (ch&7)] = (unsigned short)pk;
        hbw[nd1*128 + c1*8 + (ch&7)] = (unsigned short)(pk >> 16);
      }
    }
  };

  // ---- prologue: pairs 0,1 staged+written; pair 2 issued; step 0 computed ----
  stageIssue(0); stageWrite(0);
  stageIssue(1); stageWrite(1);
  stageIssue(2);
  __syncthreads();

  f32x4 Ar, Az, An, Br, Bz, Bn, Hn;
  xPart(0, Ar, Az, An);
  Hn = (f32x4){b_hn, b_hn, b_hn, b_hn};      // h(-1) = 0
  gates(0, Ar, Az, An, Hn);
  xPart(1, Br, Bz, Bn);

  for (int tp = 0; tp < 7; ++tp){
    const int t1 = 2*tp + 1, t2 = 2*tp + 2;
    GRU_BARRIER();                             // A: publish h(t1-1); pair tp reads done
    if (tp <= 5) stageWrite(tp + 2);           // data issued one iteration ago
    if (tp <= 4) stageIssue(tp + 3);           // flies ~2 steps before consumption
    hPart(t1, Br, Bz, Hn);
    gates(t1, Br, Bz, Bn, Hn);
    xPart(t2, Ar, Az, An);
    GRU_BARRIER();                             // B: publish h(t1)
    hPart(t2, Ar, Az, Hn);
    gates(t2, Ar, Az, An, Hn);
    xPart(t2 + 1, Br, Bz, Bn);
  }
  GRU_BARRIER();
  hPart(15, Br, Bz, Hn);
  gates(15, Br, Bz, Bn, Hn);

  #pragma unroll
  for (int q=0; q<4; ++q){
    int n = tile*16 + grp*4 + q;
    if (n < N) hout[(size_t)n*128 + ch] = hreg[q];
  }
}

// ---------------- GAT linear (MFMA) + fused attention scalars; x stored bf16 ----------------
__global__ __launch_bounds__(256) void k_gat1(
    const float* __restrict__ hsrc, const unsigned short* __restrict__ lin_sw,
    const float* __restrict__ att_s, const float* __restrict__ att_d,
    unsigned short* __restrict__ xbf, float* __restrict__ a_s, float* __restrict__ a_d,
    int N, int nT)
{
  __shared__ unsigned short Llds[16384];
  const int tid = threadIdx.x;
  for (int i = tid; i < 2048; i += 256)
    ((uint4*)Llds)[i] = ((const uint4*)lin_sw)[i];
  __syncthreads();
  const int lane = tid & 63, wloc = tid >> 6;
  const int col4 = lane & 15, grp = lane >> 4;
  const int tile = blockIdx.x*4 + wloc;
  if (tile >= nT) return;
  float ats[8], atd[8];
  #pragma unroll
  for (int ct=0;ct<8;++ct){ ats[ct] = att_s[ct*16+col4]; atd[ct] = att_d[ct*16+col4]; }
  int nrow = tile*16 + col4; if (nrow >= N) nrow = N-1;
  const float* xr = hsrc + (size_t)nrow*128 + grp*8;
  bf16x8 xa[4];
  #pragma unroll
  for (int kt=0;kt<4;++kt){
    f32x4 lo = *(const f32x4*)(xr + kt*32);
    f32x4 hi = *(const f32x4*)(xr + kt*32 + 4);
    BF8 u;
    #pragma unroll
    for (int j=0;j<4;++j){ u.s[j]=f2bf(lo[j]); u.s[4+j]=f2bf(hi[j]); }
    xa[kt] = u.v;
  }
  f32x4 acc[8];
  #pragma unroll
  for (int ct=0;ct<8;++ct) acc[ct] = (f32x4)0.0f;
  #pragma unroll
  for (int kt=0;kt<4;++kt){
    #pragma unroll
    for (int ct=0;ct<8;++ct){
      int row = ct*16+col4;
      const bf16x8 b = *(const bf16x8*)(Llds + row*128 + (((kt*4+grp)^(row&7))<<3));
      acc[ct] = __builtin_amdgcn_mfma_f32_16x16x32_bf16(xa[kt], b, acc[ct], 0,0,0);
    }
  }
  float ss[4] = {0,0,0,0}, dd[4] = {0,0,0,0};
  #pragma unroll
  for (int ct=0;ct<8;++ct)
    #pragma unroll
    for (int q=0;q<4;++q){
      float xv = acc[ct][q];
      int n = tile*16 + grp*4 + q;
      if (n < N) xbf[(size_t)n*128 + ct*16 + col4] = f2bf(xv);
      ss[q] += xv * ats[ct];
      dd[q] += xv * atd[ct];
    }
  #pragma unroll
  for (int m=1; m<16; m<<=1){
    #pragma unroll
    for (int q=0;q<4;++q){
      ss[q] += __shfl_xor(ss[q], m);
      dd[q] += __shfl_xor(dd[q], m);
    }
  }
  if (col4 == 0){
    #pragma unroll
    for (int q=0;q<4;++q){
      int n = tile*16 + grp*4 + q;
      if (n < N){ a_s[n] = ss[q]; a_d[n] = dd[q]; }
    }
  }
}

// ---------------- CSR aggregation: one wave per destination node, 4x unrolled ----------------
__global__ __launch_bounds__(256) void k_agg2(
    const int* __restrict__ off, const int* __restrict__ eid,
    const float* __restrict__ a_s, const float* __restrict__ a_d,
    const unsigned short* __restrict__ xbf, const float* __restrict__ bias,
    float* __restrict__ out2, int N)
{
  int d = blockIdx.x*4 + (threadIdx.x >> 6);
  if (d >= N) return;
  const int lane = threadIdx.x & 63;
  const unsigned* xw = (const unsigned*)xbf;   // 2 bf16 channels per uint
  const float ad_d = a_d[d];
  float a0 = a_s[d] + ad_d; a0 = a0 > 0.f ? a0 : 0.2f*a0;
  float w = __expf(a0);
  unsigned pv = xw[(size_t)d*64 + lane];
  float den  = w;
  float acc0 = w * bf2f((unsigned short)(pv & 0xffffu));
  float acc1 = w * bf2f((unsigned short)(pv >> 16));
  int i = off[d];
  const int i1 = off[d+1];
  for (; i + 3 < i1; i += 4){
    int s0 = eid[i], s1 = eid[i+1], s2 = eid[i+2], s3 = eid[i+3];
    unsigned p0 = xw[(size_t)s0*64 + lane];
    unsigned p1 = xw[(size_t)s1*64 + lane];
    unsigned p2 = xw[(size_t)s2*64 + lane];
    unsigned p3 = xw[(size_t)s3*64 + lane];
    float b0 = a_s[s0] + ad_d, b1 = a_s[s1] + ad_d, b2 = a_s[s2] + ad_d, b3 = a_s[s3] + ad_d;
    b0 = b0 > 0.f ? b0 : 0.2f*b0;  b1 = b1 > 0.f ? b1 : 0.2f*b1;
    b2 = b2 > 0.f ? b2 : 0.2f*b2;  b3 = b3 > 0.f ? b3 : 0.2f*b3;
    float w0 = __expf(b0), w1 = __expf(b1), w2 = __expf(b2), w3 = __expf(b3);
    den += w0 + w1 + w2 + w3;
    acc0 += w0 * bf2f((unsigned short)(p0 & 0xffffu)) + w1 * bf2f((unsigned short)(p1 & 0xffffu))
          + w2 * bf2f((unsigned short)(p2 & 0xffffu)) + w3 * bf2f((unsigned short)(p3 & 0xffffu));
    acc1 += w0 * bf2f((unsigned short)(p0 >> 16)) + w1 * bf2f((unsigned short)(p1 >> 16))
          + w2 * bf2f((unsigned short)(p2 >> 16)) + w3 * bf2f((unsigned short)(p3 >> 16));
  }
  for (; i < i1; ++i){
    int s = eid[i];
    float a = a_s[s] + ad_d; a = a > 0.f ? a : 0.2f*a;
    float ww = __expf(a);
    unsigned pp = xw[(size_t)s*64 + lane];
    den  += ww;
    acc0 += ww * bf2f((unsigned short)(pp & 0xffffu));
    acc1 += ww * bf2f((unsigned short)(pp >> 16));
  }
  float inv = 1.0f/den;
  float2 o;
  o.x = acc0*inv + bias[2*lane];
  o.y = acc1*inv + bias[2*lane+1];
  *(float2*)(out2 + (size_t)d*128 + 2*lane) = o;
}

extern "C" void kernel_launch(void* const* d_in, const int* in_sizes, int n_in,
                              void* d_out, int out_size, void* d_ws, size_t ws_size,
                              hipStream_t stream)
{
  const float* seq  = (const float*)d_in[0];
  const void*  ei   = d_in[1];
  const float* Wihf = (const float*)d_in[2];
  const float* Whhf = (const float*)d_in[3];
  const float* bih  = (const float*)d_in[4];
  const float* bhh  = (const float*)d_in[5];
  const float* linw = (const float*)d_in[6];
  const float* atts = (const float*)d_in[7];
  const float* attd = (const float*)d_in[8];
  const float* gbias= (const float*)d_in[9];

  const int N  = in_sizes[0] / (16*128);
  const int E  = in_sizes[1] / 2;
  const int nT = (N + 15) / 16;
  const int nB = (N + 1023) / 1024;

  char* ws = (char*)d_ws;
  size_t off_b = 0;
  auto alloc = [&](size_t bytes) -> char* {
    char* p = ws + off_b;
    off_b = (off_b + bytes + 255) & ~(size_t)255;
    return p;
  };
  unsigned short* Wih_sw = (unsigned short*)alloc(98304);
  unsigned short* Whh_sw = (unsigned short*)alloc(98304);
  unsigned short* lin_sw = (unsigned short*)alloc(32768);
  unsigned short* xbf    = (unsigned short*)alloc((size_t)N*128*2);
  float*    a_s    = (float*)   alloc((size_t)N*4);
  float*    a_d    = (float*)   alloc((size_t)N*4);
  unsigned* flag   = (unsigned*)alloc(64);
  int*      srcA   = (int*)     alloc((size_t)E*4);
  int*      dstA   = (int*)     alloc((size_t)E*4);
  int*      deg    = (int*)     alloc((size_t)N*4);
  int*      offs   = (int*)     alloc((size_t)(N+1)*4);
  int*      cur    = (int*)     alloc((size_t)N*4);
  int*      eid    = (int*)     alloc((size_t)E*4);
  int*      bsum   = (int*)     alloc((size_t)(nB+1)*4);
  int*      total  = (int*)     alloc(64);

  float* hout = (float*)d_out;
  float* out2 = hout + (size_t)N*128;

  k_prep   <<<448, 256, 0, stream>>>(Wihf, Whhf, linw, Wih_sw, Whh_sw, lin_sw);
  k_detzero<<<(N + 255)/256, 256, 0, stream>>>((const int*)ei, flag, deg, N);
  k_norm   <<<(E + 255)/256, 256, 0, stream>>>(ei, flag, srcA, dstA, deg, E);
  k_scanA  <<<nB, 256, 0, stream>>>(deg, offs, bsum, N);
  k_scanB  <<<1, 64, 0, stream>>>(bsum, total, nB);
  k_scanC  <<<(N + 255)/256, 256, 0, stream>>>(offs, bsum, total, cur, N);
  k_scatter<<<(E + 255)/256, 256, 0, stream>>>(srcA, dstA, offs, cur, eid, E);

  k_gru_fused<<<nT, 512, 0, stream>>>(Wih_sw, Whh_sw, bih, bhh, seq, hout, nT, N);

  k_gat1<<<(nT + 3)/4, 256, 0, stream>>>(hout, lin_sw, atts, attd, xbf, a_s, a_d, N, nT);
  k_agg2<<<(N + 3)/4, 256, 0, stream>>>(offs, eid, a_s, a_d, xbf, gbias, out2, N);
}

// Round 14
// 196.016 us; speedup vs baseline: 1.2305x; 1.1694x over previous
//
#include <hip/hip_runtime.h>

typedef __bf16 bf16x8 __attribute__((ext_vector_type(8)));
typedef float  f32x4  __attribute__((ext_vector_type(4)));
union BF8 { unsigned short s[8]; bf16x8 v; };

#define LOG2E 1.44269504088896340736f

// LDS-only barrier (no vmcnt drain) — measured equal to __syncthreads, kept.
#define GRU_BARRIER() asm volatile("s_waitcnt lgkmcnt(0)\n\ts_barrier" ::: "memory")

__device__ __forceinline__ unsigned short f2bf(float x){
  unsigned u = __float_as_uint(x);
  u += 0x7fffu + ((u >> 16) & 1u);      // round-to-nearest-even
  return (unsigned short)(u >> 16);
}
__device__ __forceinline__ unsigned cvt_pk_bf16(float lo, float hi){
  unsigned r;
  asm("v_cvt_pk_bf16_f32 %0, %1, %2" : "=v"(r) : "v"(lo), "v"(hi));
  return r;
}
__device__ __forceinline__ float exp2_fast(float x){   // v_exp_f32 = 2^x
  float r; asm("v_exp_f32 %0, %1" : "=v"(r) : "v"(x)); return r;
}
__device__ __forceinline__ float rcp_fast(float x){    // v_rcp_f32, 1 instr (vs IEEE div seq)
  float r; asm("v_rcp_f32 %0, %1" : "=v"(r) : "v"(x)); return r;
}
__device__ __forceinline__ float bf2f(unsigned short s){ return __uint_as_float(((unsigned)s) << 16); }

// ---------------- prep: W -> bf16 pre-swizzled; r,z rows xLOG2E, n rows x2LOG2E ---------
__global__ void k_prep(const float* __restrict__ Wihf, const float* __restrict__ Whhf,
                       const float* __restrict__ linw,
                       unsigned short* __restrict__ Wih_sw, unsigned short* __restrict__ Whh_sw,
                       unsigned short* __restrict__ lin_sw)
{
  int tid = blockIdx.x*256 + threadIdx.x;
  if (tid < 49152){
    int row = tid >> 7, col = tid & 127;
    float sc = (row < 256) ? LOG2E : 2.0f*LOG2E;
    Wih_sw[row*128 + (((col>>3) ^ (row&7))<<3) + (col&7)] = f2bf(Wihf[tid]*sc);
  } else if (tid < 98304){
    int i = tid - 49152; int row = i >> 7, col = i & 127;
    float sc = (row < 256) ? LOG2E : 2.0f*LOG2E;
    Whh_sw[row*128 + (((col>>3) ^ (row&7))<<3) + (col&7)] = f2bf(Whhf[i]*sc);
  } else if (tid < 114688){
    int i = tid - 98304; int row = i >> 7, col = i & 127;
    lin_sw[row*128 + (((col>>3) ^ (row&7))<<3) + (col&7)] = f2bf(linw[i]);
  }
}

// ---------------- edge dtype sniff + deg zero (merged) ----------------
__global__ void k_detzero(const int* __restrict__ ei, unsigned* __restrict__ flag,
                          int* __restrict__ deg, int N){
  int tid = blockIdx.x*256 + threadIdx.x;
  if (tid < N) deg[tid] = 0;
  if (blockIdx.x == 0 && threadIdx.x < 64){
    int v = ei[2*threadIdx.x + 1];
    unsigned long long b = __ballot(v == 0);
    if (threadIdx.x == 0) flag[0] = (b == ~0ULL) ? 1u : 0u;
  }
}

__global__ void k_norm(const void* __restrict__ ei, const unsigned* __restrict__ flag,
                       int* __restrict__ src, int* __restrict__ dst, int* __restrict__ deg, int E){
  int e = blockIdx.x*256 + threadIdx.x;
  if (e >= E) return;
  int s, d;
  if (flag[0]){
    const long long* p = (const long long*)ei;
    s = (int)p[e]; d = (int)p[(size_t)E + e];
  } else {
    const int* p = (const int*)ei;
    s = p[e]; d = p[E + e];
  }
  src[e] = s; dst[e] = d;
  atomicAdd(&deg[d], 1);
}

// ---------------- parallel 3-level exclusive scan of deg -> off ----------------
__global__ __launch_bounds__(256) void k_scanA(const int* __restrict__ deg,
    int* __restrict__ off, int* __restrict__ bsum, int N){
  __shared__ int wsum[4];
  const int b = blockIdx.x, t = threadIdx.x;
  const int lane = t & 63, wv = t >> 6;
  const int base = b*1024 + t*4;
  int v[4]; int s = 0;
  #pragma unroll
  for (int j=0;j<4;++j){ v[j] = (base+j < N) ? deg[base+j] : 0; s += v[j]; }
  int inc = s;
  #pragma unroll
  for (int d2=1; d2<64; d2<<=1){ int u = __shfl_up(inc, d2); if (lane >= d2) inc += u; }
  if (lane == 63) wsum[wv] = inc;
  __syncthreads();
  int woff = 0;
  #pragma unroll
  for (int j=0;j<4;++j) if (j < wv) woff += wsum[j];
  int ex = woff + inc - s;
  #pragma unroll
  for (int j=0;j<4;++j){
    if (base+j < N) off[base+j] = ex;
    ex += v[j];
  }
  if (t == 255) bsum[b] = woff + inc;
}

__global__ void k_scanB(int* __restrict__ bsum, int* __restrict__ total, int nB){
  int lane = threadIdx.x;
  int carry = 0;
  for (int base = 0; base < nB; base += 64){
    int i = base + lane;
    int v = (i < nB) ? bsum[i] : 0;
    int inc = v;
    #pragma unroll
    for (int d2=1; d2<64; d2<<=1){ int u = __shfl_up(inc, d2); if (lane >= d2) inc += u; }
    if (i < nB) bsum[i] = carry + inc - v;
    carry += __shfl(inc, 63);
  }
  if (lane == 0) total[0] = carry;
}

__global__ void k_scanC(int* __restrict__ off, const int* __restrict__ bsum,
    const int* __restrict__ total, int* __restrict__ cur, int N){
  int i = blockIdx.x*256 + threadIdx.x;
  if (i < N){ off[i] += bsum[i>>10]; cur[i] = 0; }
  if (i == 0) off[N] = total[0];
}

__global__ void k_scatter(const int* __restrict__ src, const int* __restrict__ dst,
                          const int* __restrict__ off, int* __restrict__ cur,
                          int* __restrict__ eid, int E){
  int e = blockIdx.x*256 + threadIdx.x;
  if (e >= E) return;
  int d = dst[e];
  int p = off[d] + atomicAdd(&cur[d], 1);
  eid[p] = src[e];
}

// ---------------- fused GRU + GAT-linear epilogue ----------------
// Weights pre-scaled: r,z by log2e (sigm = rcp(1+2^-x)), n by 2log2e (tanh = 1-2*rcp(2^s+1)).
// gates(15) publishes h(15) to hbuf[0]; epilogue computes x = h@lin^T, a_s, a_d in-block.
__global__ __launch_bounds__(512, 2) void k_gru_fused(
    const unsigned short* __restrict__ Wih_sw, const unsigned short* __restrict__ Whh_sw,
    const unsigned short* __restrict__ lin_sw,
    const float* __restrict__ bih, const float* __restrict__ bhh,
    const float* __restrict__ att_s, const float* __restrict__ att_d,
    const float* __restrict__ seq, float* __restrict__ hout,
    unsigned short* __restrict__ xbf, float* __restrict__ a_s, float* __restrict__ a_d,
    int nT, int N)
{
  __shared__ unsigned short xbuf[2][16*256];   // [slot][node][s(2 steps)][ch swz]
  __shared__ unsigned short hbuf[2][16*128];   // [buf][node][ch swz]
  __shared__ float redS[8][16], redD[8][16];
  const int tid  = threadIdx.x;
  const int lane = tid & 63, w = tid >> 6;     // w = channel chunk 0..7
  const int col4 = lane & 15, grp = lane >> 4;
  const int tile = blockIdx.x;
  const int ch   = 16*w + col4;                // this lane's output channel

  bf16x8 Wf[6][4], Lf[4];
  #pragma unroll
  for (int s6=0; s6<6; ++s6){
    const unsigned short* Wp = (s6 < 3) ? Wih_sw : Whh_sw;
    int row = (s6 % 3)*128 + ch;
    #pragma unroll
    for (int kt=0; kt<4; ++kt)
      Wf[s6][kt] = *(const bf16x8*)(Wp + row*128 + (((kt*4+grp) ^ (row&7))<<3));
  }
  #pragma unroll
  for (int kt=0; kt<4; ++kt)
    Lf[kt] = *(const bf16x8*)(lin_sw + ch*128 + (((kt*4+grp) ^ (ch&7))<<3));
  const float brz_r = (bih[ch]       + bhh[ch])       * LOG2E;
  const float brz_z = (bih[128 + ch] + bhh[128 + ch]) * LOG2E;
  const float b_xn  = bih[256 + ch] * (2.0f*LOG2E);
  const float b_hn  = bhh[256 + ch] * (2.0f*LOG2E);
  const float ats   = att_s[ch];
  const float atd   = att_d[ch];

  float hreg[4] = {0.f, 0.f, 0.f, 0.f};

  f32x4 sv[2];
  auto stageIssue = [&](int p){               // load pair p (steps 2p,2p+1)
    #pragma unroll
    for (int rr=0; rr<2; ++rr){
      int nrow = tile*16 + 2*w + rr; if (nrow >= N) nrow = N-1;
      sv[rr] = *(const f32x4*)(seq + ((size_t)nrow*16 + 2*p)*128 + lane*4);
    }
  };
  auto stageWrite = [&](int p){
    const int s  = lane >> 5;
    const int c0 = (lane & 31) * 4;
    #pragma unroll
    for (int rr=0; rr<2; ++rr){
      int node = 2*w + rr;
      int chunk = (c0 >> 3) ^ node;
      uint2 pk;
      pk.x = cvt_pk_bf16(sv[rr][0], sv[rr][1]);
      pk.y = cvt_pk_bf16(sv[rr][2], sv[rr][3]);
      *(uint2*)(&xbuf[p & 1][node*256 + s*128 + chunk*8 + (c0 & 7)]) = pk;
    }
  };

  auto xPart = [&](int t, f32x4& nr, f32x4& nz, f32x4& nn){
    bf16x8 xa[4];
    const unsigned short* xb = xbuf[(t>>1)&1] + col4*256 + (t&1)*128;
    #pragma unroll
    for (int kt=0;kt<4;++kt){
      int chunk = (kt*4+grp) ^ col4;
      xa[kt] = *(const bf16x8*)(xb + chunk*8);
    }
    nr = (f32x4){brz_r, brz_r, brz_r, brz_r};
    nz = (f32x4){brz_z, brz_z, brz_z, brz_z};
    nn = (f32x4){b_xn,  b_xn,  b_xn,  b_xn };
    #pragma unroll
    for (int kt=0; kt<4; ++kt){
      nr = __builtin_amdgcn_mfma_f32_16x16x32_bf16(xa[kt], Wf[0][kt], nr, 0,0,0);
      nz = __builtin_amdgcn_mfma_f32_16x16x32_bf16(xa[kt], Wf[1][kt], nz, 0,0,0);
      nn = __builtin_amdgcn_mfma_f32_16x16x32_bf16(xa[kt], Wf[2][kt], nn, 0,0,0);
    }
  };
  auto hPart = [&](int t, f32x4& cr, f32x4& cz, f32x4& chn){
    bf16x8 ha[4];
    const unsigned short* hb = hbuf[t&1];
    #pragma unroll
    for (int kt=0;kt<4;++kt){
      int chunk = (kt*4+grp) ^ col4;
      ha[kt] = *(const bf16x8*)(hb + col4*128 + chunk*8);
    }
    chn = (f32x4){b_hn, b_hn, b_hn, b_hn};
    #pragma unroll
    for (int kt=0; kt<4; ++kt){
      cr  = __builtin_amdgcn_mfma_f32_16x16x32_bf16(ha[kt], Wf[3][kt], cr , 0,0,0);
      cz  = __builtin_amdgcn_mfma_f32_16x16x32_bf16(ha[kt], Wf[4][kt], cz , 0,0,0);
      chn = __builtin_amdgcn_mfma_f32_16x16x32_bf16(ha[kt], Wf[5][kt], chn, 0,0,0);
    }
  };
  // activations with pre-scaled logits: sigm = rcp(1+2^-x); tanh = 1-2*rcp(2^s+1)
  auto gates = [&](int t, const f32x4& cr, const f32x4& cz, const f32x4& cn, const f32x4& chn){
    unsigned short* hbw = hbuf[(t+1)&1];
    #pragma unroll
    for (int q=0; q<4; q+=2){
      float r0 = rcp_fast(1.0f + exp2_fast(-cr[q]));
      float z0 = rcp_fast(1.0f + exp2_fast(-cz[q]));
      float n0 = 1.0f - 2.0f*rcp_fast(exp2_fast(cn[q]   + r0*chn[q])   + 1.0f);
      float h0 = n0 + z0*(hreg[q]   - n0); hreg[q]   = h0;
      float r1 = rcp_fast(1.0f + exp2_fast(-cr[q+1]));
      float z1 = rcp_fast(1.0f + exp2_fast(-cz[q+1]));
      float n1 = 1.0f - 2.0f*rcp_fast(exp2_fast(cn[q+1] + r1*chn[q+1]) + 1.0f);
      float h1 = n1 + z1*(hreg[q+1] - n1); hreg[q+1] = h1;
      unsigned pk = cvt_pk_bf16(h0, h1);
      int nd0 = grp*4 + q, nd1 = nd0 + 1;
      int c0 = ((ch>>3) ^ nd0), c1 = ((ch>>3) ^ nd1);
      hbw[nd0*128 + c0*8 + (ch&7)] = (unsigned short)pk;
      hbw[nd1*128 + c1*8 + (ch&7)] = (unsigned short)(pk >> 16);
    }
  };

  // ---- prologue ----
  stageIssue(0); stageWrite(0);
  stageIssue(1); stageWrite(1);
  stageIssue(2);
  __syncthreads();

  f32x4 Ar, Az, An, Br, Bz, Bn, Hn;
  xPart(0, Ar, Az, An);
  Hn = (f32x4){b_hn, b_hn, b_hn, b_hn};      // h(-1) = 0
  gates(0, Ar, Az, An, Hn);
  xPart(1, Br, Bz, Bn);

  for (int tp = 0; tp < 7; ++tp){
    const int t1 = 2*tp + 1, t2 = 2*tp + 2;
    GRU_BARRIER();
    if (tp <= 5) stageWrite(tp + 2);
    if (tp <= 4) stageIssue(tp + 3);
    hPart(t1, Br, Bz, Hn);
    gates(t1, Br, Bz, Bn, Hn);
    xPart(t2, Ar, Az, An);
    GRU_BARRIER();
    hPart(t2, Ar, Az, Hn);
    gates(t2, Ar, Az, An, Hn);
    xPart(t2 + 1, Br, Bz, Bn);
  }
  GRU_BARRIER();
  hPart(15, Br, Bz, Hn);
  gates(15, Br, Bz, Bn, Hn);           // also publishes h(15) into hbuf[0]

  #pragma unroll
  for (int q=0; q<4; ++q){
    int n = tile*16 + grp*4 + q;
    if (n < N) hout[(size_t)n*128 + ch] = hreg[q];
  }

  // ---- epilogue: x = h @ lin^T (per-wave 16 out channels), a_s/a_d dots ----
  GRU_BARRIER();
  {
    bf16x8 ha[4];
    const unsigned short* hb = hbuf[0];
    #pragma unroll
    for (int kt=0;kt<4;++kt){
      int chunk = (kt*4+grp) ^ col4;
      ha[kt] = *(const bf16x8*)(hb + col4*128 + chunk*8);
    }
    f32x4 acc = (f32x4)0.0f;
    #pragma unroll
    for (int kt=0; kt<4; ++kt)
      acc = __builtin_amdgcn_mfma_f32_16x16x32_bf16(ha[kt], Lf[kt], acc, 0,0,0);
    float ssq[4], ddq[4];
    #pragma unroll
    for (int q=0;q<4;++q){
      float xv = acc[q];
      int n = tile*16 + grp*4 + q;
      if (n < N) xbf[(size_t)n*128 + ch] = f2bf(xv);
      ssq[q] = xv * ats;
      ddq[q] = xv * atd;
    }
    #pragma unroll
    for (int m=1; m<16; m<<=1){
      #pragma unroll
      for (int q=0;q<4;++q){
        ssq[q] += __shfl_xor(ssq[q], m);
        ddq[q] += __shfl_xor(ddq[q], m);
      }
    }
    if (col4 == 0){
      #pragma unroll
      for (int q=0;q<4;++q){
        redS[w][grp*4+q] = ssq[q];
        redD[w][grp*4+q] = ddq[q];
      }
    }
    __syncthreads();
    if (w == 0 && lane < 16){
      float s = 0.f, d = 0.f;
      #pragma unroll
      for (int k=0;k<8;++k){ s += redS[k][lane]; d += redD[k][lane]; }
      int n = tile*16 + lane;
      if (n < N){ a_s[n] = s; a_d[n] = d; }
    }
  }
}

// ---------------- CSR aggregation: one wave per destination node, 8x unrolled ----------------
__global__ __launch_bounds__(256) void k_agg2(
    const int* __restrict__ off, const int* __restrict__ eid,
    const float* __restrict__ a_s, const float* __restrict__ a_d,
    const unsigned short* __restrict__ xbf, const float* __restrict__ bias,
    float* __restrict__ out2, int N)
{
  int d = blockIdx.x*4 + (threadIdx.x >> 6);
  if (d >= N) return;
  const int lane = threadIdx.x & 63;
  const unsigned* xw = (const unsigned*)xbf;   // 2 bf16 channels per uint
  const float ad_d = a_d[d];
  float a0 = a_s[d] + ad_d; a0 = a0 > 0.f ? a0 : 0.2f*a0;
  float w = __expf(a0);
  unsigned pv = xw[(size_t)d*64 + lane];
  float den  = w;
  float acc0 = w * bf2f((unsigned short)(pv & 0xffffu));
  float acc1 = w * bf2f((unsigned short)(pv >> 16));
  int i = off[d];
  const int i1 = off[d+1];
  for (; i + 7 < i1; i += 8){
    int   sj[8]; unsigned pj[8]; float bj[8];
    #pragma unroll
    for (int j=0;j<8;++j) sj[j] = eid[i+j];
    #pragma unroll
    for (int j=0;j<8;++j) pj[j] = xw[(size_t)sj[j]*64 + lane];
    #pragma unroll
    for (int j=0;j<8;++j){
      float b = a_s[sj[j]] + ad_d;
      bj[j] = b > 0.f ? b : 0.2f*b;
    }
    #pragma unroll
    for (int j=0;j<8;++j){
      float ww = __expf(bj[j]);
      den  += ww;
      acc0 += ww * bf2f((unsigned short)(pj[j] & 0xffffu));
      acc1 += ww * bf2f((unsigned short)(pj[j] >> 16));
    }
  }
  for (; i + 3 < i1; i += 4){
    int s0 = eid[i], s1 = eid[i+1], s2 = eid[i+2], s3 = eid[i+3];
    unsigned p0 = xw[(size_t)s0*64 + lane];
    unsigned p1 = xw[(size_t)s1*64 + lane];
    unsigned p2 = xw[(size_t)s2*64 + lane];
    unsigned p3 = xw[(size_t)s3*64 + lane];
    float b0 = a_s[s0] + ad_d, b1 = a_s[s1] + ad_d, b2 = a_s[s2] + ad_d, b3 = a_s[s3] + ad_d;
    b0 = b0 > 0.f ? b0 : 0.2f*b0;  b1 = b1 > 0.f ? b1 : 0.2f*b1;
    b2 = b2 > 0.f ? b2 : 0.2f*b2;  b3 = b3 > 0.f ? b3 : 0.2f*b3;
    float w0 = __expf(b0), w1 = __expf(b1), w2 = __expf(b2), w3 = __expf(b3);
    den += w0 + w1 + w2 + w3;
    acc0 += w0 * bf2f((unsigned short)(p0 & 0xffffu)) + w1 * bf2f((unsigned short)(p1 & 0xffffu))
          + w2 * bf2f((unsigned short)(p2 & 0xffffu)) + w3 * bf2f((unsigned short)(p3 & 0xffffu));
    acc1 += w0 * bf2f((unsigned short)(p0 >> 16)) + w1 * bf2f((unsigned short)(p1 >> 16))
          + w2 * bf2f((unsigned short)(p2 >> 16)) + w3 * bf2f((unsigned short)(p3 >> 16));
  }
  for (; i < i1; ++i){
    int s = eid[i];
    float a = a_s[s] + ad_d; a = a > 0.f ? a : 0.2f*a;
    float ww = __expf(a);
    unsigned pp = xw[(size_t)s*64 + lane];
    den  += ww;
    acc0 += ww * bf2f((unsigned short)(pp & 0xffffu));
    acc1 += ww * bf2f((unsigned short)(pp >> 16));
  }
  float inv = rcp_fast(den);
  float2 o;
  o.x = acc0*inv + bias[2*lane];
  o.y = acc1*inv + bias[2*lane+1];
  *(float2*)(out2 + (size_t)d*128 + 2*lane) = o;
}

extern "C" void kernel_launch(void* const* d_in, const int* in_sizes, int n_in,
                              void* d_out, int out_size, void* d_ws, size_t ws_size,
                              hipStream_t stream)
{
  const float* seq  = (const float*)d_in[0];
  const void*  ei   = d_in[1];
  const float* Wihf = (const float*)d_in[2];
  const float* Whhf = (const float*)d_in[3];
  const float* bih  = (const float*)d_in[4];
  const float* bhh  = (const float*)d_in[5];
  const float* linw = (const float*)d_in[6];
  const float* atts = (const float*)d_in[7];
  const float* attd = (const float*)d_in[8];
  const float* gbias= (const float*)d_in[9];

  const int N  = in_sizes[0] / (16*128);
  const int E  = in_sizes[1] / 2;
  const int nT = (N + 15) / 16;
  const int nB = (N + 1023) / 1024;

  char* ws = (char*)d_ws;
  size_t off_b = 0;
  auto alloc = [&](size_t bytes) -> char* {
    char* p = ws + off_b;
    off_b = (off_b + bytes + 255) & ~(size_t)255;
    return p;
  };
  unsigned short* Wih_sw = (unsigned short*)alloc(98304);
  unsigned short* Whh_sw = (unsigned short*)alloc(98304);
  unsigned short* lin_sw = (unsigned short*)alloc(32768);
  unsigned short* xbf    = (unsigned short*)alloc((size_t)N*128*2);
  float*    a_s    = (float*)   alloc((size_t)N*4);
  float*    a_d    = (float*)   alloc((size_t)N*4);
  unsigned* flag   = (unsigned*)alloc(64);
  int*      srcA   = (int*)     alloc((size_t)E*4);
  int*      dstA   = (int*)     alloc((size_t)E*4);
  int*      deg    = (int*)     alloc((size_t)N*4);
  int*      offs   = (int*)     alloc((size_t)(N+1)*4);
  int*      cur    = (int*)     alloc((size_t)N*4);
  int*      eid    = (int*)     alloc((size_t)E*4);
  int*      bsum   = (int*)     alloc((size_t)(nB+1)*4);
  int*      total  = (int*)     alloc(64);

  float* hout = (float*)d_out;
  float* out2 = hout + (size_t)N*128;

  k_prep   <<<448, 256, 0, stream>>>(Wihf, Whhf, linw, Wih_sw, Whh_sw, lin_sw);
  k_detzero<<<(N + 255)/256, 256, 0, stream>>>((const int*)ei, flag, deg, N);
  k_norm   <<<(E + 255)/256, 256, 0, stream>>>(ei, flag, srcA, dstA, deg, E);
  k_scanA  <<<nB, 256, 0, stream>>>(deg, offs, bsum, N);
  k_scanB  <<<1, 64, 0, stream>>>(bsum, total, nB);
  k_scanC  <<<(N + 255)/256, 256, 0, stream>>>(offs, bsum, total, cur, N);
  k_scatter<<<(E + 255)/256, 256, 0, stream>>>(srcA, dstA, offs, cur, eid, E);

  k_gru_fused<<<nT, 512, 0, stream>>>(Wih_sw, Whh_sw, lin_sw, bih, bhh, atts, attd,
                                      seq, hout, xbf, a_s, a_d, nT, N);

  k_agg2<<<(N + 3)/4, 256, 0, stream>>>(offs, eid, a_s, a_d, xbf, gbias, out2, N);
}

// Round 15
// 188.509 us; speedup vs baseline: 1.2795x; 1.0398x over previous
//
#include <hip/hip_runtime.h>

typedef __bf16 bf16x8 __attribute__((ext_vector_type(8)));
typedef float  f32x4  __attribute__((ext_vector_type(4)));
union BF8 { unsigned short s[8]; bf16x8 v; };

#define LOG2E 1.44269504088896340736f

// LDS-only barrier (no vmcnt drain).
#define GRU_BARRIER() asm volatile("s_waitcnt lgkmcnt(0)\n\ts_barrier" ::: "memory")

__device__ __forceinline__ unsigned short f2bf(float x){
  unsigned u = __float_as_uint(x);
  u += 0x7fffu + ((u >> 16) & 1u);      // round-to-nearest-even
  return (unsigned short)(u >> 16);
}
__device__ __forceinline__ unsigned cvt_pk_bf16(float lo, float hi){
  unsigned r;
  asm("v_cvt_pk_bf16_f32 %0, %1, %2" : "=v"(r) : "v"(lo), "v"(hi));
  return r;
}
__device__ __forceinline__ float exp2_fast(float x){   // v_exp_f32 = 2^x
  float r; asm("v_exp_f32 %0, %1" : "=v"(r) : "v"(x)); return r;
}
__device__ __forceinline__ float rcp_fast(float x){    // v_rcp_f32
  float r; asm("v_rcp_f32 %0, %1" : "=v"(r) : "v"(x)); return r;
}
__device__ __forceinline__ float bf2f(unsigned short s){ return __uint_as_float(((unsigned)s) << 16); }

// ---------------- prep: W -> bf16 pre-swizzled; r,z rows xLOG2E, n rows x2LOG2E ---------
__global__ void k_prep(const float* __restrict__ Wihf, const float* __restrict__ Whhf,
                       const float* __restrict__ linw,
                       unsigned short* __restrict__ Wih_sw, unsigned short* __restrict__ Whh_sw,
                       unsigned short* __restrict__ lin_sw)
{
  int tid = blockIdx.x*256 + threadIdx.x;
  if (tid < 49152){
    int row = tid >> 7, col = tid & 127;
    float sc = (row < 256) ? LOG2E : 2.0f*LOG2E;
    Wih_sw[row*128 + (((col>>3) ^ (row&7))<<3) + (col&7)] = f2bf(Wihf[tid]*sc);
  } else if (tid < 98304){
    int i = tid - 49152; int row = i >> 7, col = i & 127;
    float sc = (row < 256) ? LOG2E : 2.0f*LOG2E;
    Whh_sw[row*128 + (((col>>3) ^ (row&7))<<3) + (col&7)] = f2bf(Whhf[i]*sc);
  } else if (tid < 114688){
    int i = tid - 98304; int row = i >> 7, col = i & 127;
    lin_sw[row*128 + (((col>>3) ^ (row&7))<<3) + (col&7)] = f2bf(linw[i]);
  }
}

// ---------------- edge dtype sniff + deg zero (merged) ----------------
__global__ void k_detzero(const int* __restrict__ ei, unsigned* __restrict__ flag,
                          int* __restrict__ deg, int N){
  int tid = blockIdx.x*256 + threadIdx.x;
  if (tid < N) deg[tid] = 0;
  if (blockIdx.x == 0 && threadIdx.x < 64){
    int v = ei[2*threadIdx.x + 1];
    unsigned long long b = __ballot(v == 0);
    if (threadIdx.x == 0) flag[0] = (b == ~0ULL) ? 1u : 0u;
  }
}

// histogram destinations straight from edge_index (no src/dst materialization)
__global__ void k_deg(const void* __restrict__ ei, const unsigned* __restrict__ flag,
                      int* __restrict__ deg, int E){
  int e = blockIdx.x*256 + threadIdx.x;
  if (e >= E) return;
  int d;
  if (flag[0]) d = (int)((const long long*)ei)[(size_t)E + e];
  else         d = ((const int*)ei)[E + e];
  atomicAdd(&deg[d], 1);
}

// ---------------- parallel 3-level exclusive scan of deg -> off ----------------
__global__ __launch_bounds__(256) void k_scanA(const int* __restrict__ deg,
    int* __restrict__ off, int* __restrict__ bsum, int N){
  __shared__ int wsum[4];
  const int b = blockIdx.x, t = threadIdx.x;
  const int lane = t & 63, wv = t >> 6;
  const int base = b*1024 + t*4;
  int v[4]; int s = 0;
  #pragma unroll
  for (int j=0;j<4;++j){ v[j] = (base+j < N) ? deg[base+j] : 0; s += v[j]; }
  int inc = s;
  #pragma unroll
  for (int d2=1; d2<64; d2<<=1){ int u = __shfl_up(inc, d2); if (lane >= d2) inc += u; }
  if (lane == 63) wsum[wv] = inc;
  __syncthreads();
  int woff = 0;
  #pragma unroll
  for (int j=0;j<4;++j) if (j < wv) woff += wsum[j];
  int ex = woff + inc - s;
  #pragma unroll
  for (int j=0;j<4;++j){
    if (base+j < N) off[base+j] = ex;
    ex += v[j];
  }
  if (t == 255) bsum[b] = woff + inc;
}

__global__ void k_scanB(int* __restrict__ bsum, int* __restrict__ total, int nB){
  int lane = threadIdx.x;
  int carry = 0;
  for (int base = 0; base < nB; base += 64){
    int i = base + lane;
    int v = (i < nB) ? bsum[i] : 0;
    int inc = v;
    #pragma unroll
    for (int d2=1; d2<64; d2<<=1){ int u = __shfl_up(inc, d2); if (lane >= d2) inc += u; }
    if (i < nB) bsum[i] = carry + inc - v;
    carry += __shfl(inc, 63);
  }
  if (lane == 0) total[0] = carry;
}

// off finalize + cur = off (scatter cursors)
__global__ void k_scanC(int* __restrict__ off, const int* __restrict__ bsum,
    const int* __restrict__ total, int* __restrict__ cur, int N){
  int i = blockIdx.x*256 + threadIdx.x;
  if (i < N){
    int o = off[i] + bsum[i>>10];
    off[i] = o; cur[i] = o;
  }
  if (i == 0) off[N] = total[0];
}

// scatter edge sources into CSR, reading edge_index directly (L3-hot 2nd pass)
__global__ void k_scatter(const void* __restrict__ ei, const unsigned* __restrict__ flag,
                          int* __restrict__ cur, int* __restrict__ eid, int E){
  int e = blockIdx.x*256 + threadIdx.x;
  if (e >= E) return;
  int s, d;
  if (flag[0]){
    const long long* p = (const long long*)ei;
    s = (int)p[e]; d = (int)p[(size_t)E + e];
  } else {
    const int* p = (const int*)ei;
    s = p[e]; d = p[E + e];
  }
  int pos = atomicAdd(&cur[d], 1);
  eid[pos] = s;
}

// ---------------- persistent fused GRU + GAT-linear epilogue ----------------
// grid = 512 (2 blocks/CU); each block loops over tiles, paying the weight
// prologue ONCE. Per tile: r7 schedule, LDS-only barriers, fast activations.
__global__ __launch_bounds__(512, 2) void k_gru_fused(
    const unsigned short* __restrict__ Wih_sw, const unsigned short* __restrict__ Whh_sw,
    const unsigned short* __restrict__ lin_sw,
    const float* __restrict__ bih, const float* __restrict__ bhh,
    const float* __restrict__ att_s, const float* __restrict__ att_d,
    const float* __restrict__ seq, float* __restrict__ hout,
    unsigned short* __restrict__ xbf, float* __restrict__ a_s, float* __restrict__ a_d,
    int nT, int N)
{
  __shared__ unsigned short xbuf[2][16*256];   // [slot][node][s(2 steps)][ch swz]
  __shared__ unsigned short hbuf[2][16*128];   // [buf][node][ch swz]
  __shared__ float redS[8][16], redD[8][16];
  const int tid  = threadIdx.x;
  const int lane = tid & 63, w = tid >> 6;     // w = channel chunk 0..7
  const int col4 = lane & 15, grp = lane >> 4;
  const int ch   = 16*w + col4;                // this lane's output channel

  bf16x8 Wf[6][4], Lf[4];
  #pragma unroll
  for (int s6=0; s6<6; ++s6){
    const unsigned short* Wp = (s6 < 3) ? Wih_sw : Whh_sw;
    int row = (s6 % 3)*128 + ch;
    #pragma unroll
    for (int kt=0; kt<4; ++kt)
      Wf[s6][kt] = *(const bf16x8*)(Wp + row*128 + (((kt*4+grp) ^ (row&7))<<3));
  }
  #pragma unroll
  for (int kt=0; kt<4; ++kt)
    Lf[kt] = *(const bf16x8*)(lin_sw + ch*128 + (((kt*4+grp) ^ (ch&7))<<3));
  const float brz_r = (bih[ch]       + bhh[ch])       * LOG2E;
  const float brz_z = (bih[128 + ch] + bhh[128 + ch]) * LOG2E;
  const float b_xn  = bih[256 + ch] * (2.0f*LOG2E);
  const float b_hn  = bhh[256 + ch] * (2.0f*LOG2E);
  const float ats   = att_s[ch];
  const float atd   = att_d[ch];

  float hreg[4];
  f32x4 sv[2];
  auto stageIssue = [&](int tile, int p){     // load pair p (steps 2p,2p+1)
    #pragma unroll
    for (int rr=0; rr<2; ++rr){
      int nrow = tile*16 + 2*w + rr; if (nrow >= N) nrow = N-1;
      sv[rr] = *(const f32x4*)(seq + ((size_t)nrow*16 + 2*p)*128 + lane*4);
    }
  };
  auto stageWrite = [&](int p){
    const int s  = lane >> 5;
    const int c0 = (lane & 31) * 4;
    #pragma unroll
    for (int rr=0; rr<2; ++rr){
      int node = 2*w + rr;
      int chunk = (c0 >> 3) ^ node;
      uint2 pk;
      pk.x = cvt_pk_bf16(sv[rr][0], sv[rr][1]);
      pk.y = cvt_pk_bf16(sv[rr][2], sv[rr][3]);
      *(uint2*)(&xbuf[p & 1][node*256 + s*128 + chunk*8 + (c0 & 7)]) = pk;
    }
  };

  auto xPart = [&](int t, f32x4& nr, f32x4& nz, f32x4& nn){
    bf16x8 xa[4];
    const unsigned short* xb = xbuf[(t>>1)&1] + col4*256 + (t&1)*128;
    #pragma unroll
    for (int kt=0;kt<4;++kt){
      int chunk = (kt*4+grp) ^ col4;
      xa[kt] = *(const bf16x8*)(xb + chunk*8);
    }
    nr = (f32x4){brz_r, brz_r, brz_r, brz_r};
    nz = (f32x4){brz_z, brz_z, brz_z, brz_z};
    nn = (f32x4){b_xn,  b_xn,  b_xn,  b_xn };
    #pragma unroll
    for (int kt=0; kt<4; ++kt){
      nr = __builtin_amdgcn_mfma_f32_16x16x32_bf16(xa[kt], Wf[0][kt], nr, 0,0,0);
      nz = __builtin_amdgcn_mfma_f32_16x16x32_bf16(xa[kt], Wf[1][kt], nz, 0,0,0);
      nn = __builtin_amdgcn_mfma_f32_16x16x32_bf16(xa[kt], Wf[2][kt], nn, 0,0,0);
    }
  };
  auto hPart = [&](int t, f32x4& cr, f32x4& cz, f32x4& chn){
    bf16x8 ha[4];
    const unsigned short* hb = hbuf[t&1];
    #pragma unroll
    for (int kt=0;kt<4;++kt){
      int chunk = (kt*4+grp) ^ col4;
      ha[kt] = *(const bf16x8*)(hb + col4*128 + chunk*8);
    }
    chn = (f32x4){b_hn, b_hn, b_hn, b_hn};
    #pragma unroll
    for (int kt=0; kt<4; ++kt){
      cr  = __builtin_amdgcn_mfma_f32_16x16x32_bf16(ha[kt], Wf[3][kt], cr , 0,0,0);
      cz  = __builtin_amdgcn_mfma_f32_16x16x32_bf16(ha[kt], Wf[4][kt], cz , 0,0,0);
      chn = __builtin_amdgcn_mfma_f32_16x16x32_bf16(ha[kt], Wf[5][kt], chn, 0,0,0);
    }
  };
  auto gates = [&](int t, const f32x4& cr, const f32x4& cz, const f32x4& cn, const f32x4& chn){
    unsigned short* hbw = hbuf[(t+1)&1];
    #pragma unroll
    for (int q=0; q<4; q+=2){
      float r0 = rcp_fast(1.0f + exp2_fast(-cr[q]));
      float z0 = rcp_fast(1.0f + exp2_fast(-cz[q]));
      float n0 = 1.0f - 2.0f*rcp_fast(exp2_fast(cn[q]   + r0*chn[q])   + 1.0f);
      float h0 = n0 + z0*(hreg[q]   - n0); hreg[q]   = h0;
      float r1 = rcp_fast(1.0f + exp2_fast(-cr[q+1]));
      float z1 = rcp_fast(1.0f + exp2_fast(-cz[q+1]));
      float n1 = 1.0f - 2.0f*rcp_fast(exp2_fast(cn[q+1] + r1*chn[q+1]) + 1.0f);
      float h1 = n1 + z1*(hreg[q+1] - n1); hreg[q+1] = h1;
      unsigned pk = cvt_pk_bf16(h0, h1);
      int nd0 = grp*4 + q, nd1 = nd0 + 1;
      int c0 = ((ch>>3) ^ nd0), c1 = ((ch>>3) ^ nd1);
      hbw[nd0*128 + c0*8 + (ch&7)] = (unsigned short)pk;
      hbw[nd1*128 + c1*8 + (ch&7)] = (unsigned short)(pk >> 16);
    }
  };

  for (int tile = blockIdx.x; tile < nT; tile += gridDim.x){
    #pragma unroll
    for (int q=0;q<4;++q) hreg[q] = 0.f;

    // per-tile prologue (xbuf WAR vs previous tile separated by epilogue syncthreads)
    stageIssue(tile, 0); stageWrite(0);
    stageIssue(tile, 1); stageWrite(1);
    stageIssue(tile, 2);
    __syncthreads();

    f32x4 Ar, Az, An, Br, Bz, Bn, Hn;
    xPart(0, Ar, Az, An);
    Hn = (f32x4){b_hn, b_hn, b_hn, b_hn};    // h(-1) = 0
    gates(0, Ar, Az, An, Hn);
    xPart(1, Br, Bz, Bn);

    for (int tp = 0; tp < 7; ++tp){
      const int t1 = 2*tp + 1, t2 = 2*tp + 2;
      GRU_BARRIER();
      if (tp <= 5) stageWrite(tp + 2);
      if (tp <= 4) stageIssue(tile, tp + 3);
      hPart(t1, Br, Bz, Hn);
      gates(t1, Br, Bz, Bn, Hn);
      xPart(t2, Ar, Az, An);
      GRU_BARRIER();
      hPart(t2, Ar, Az, Hn);
      gates(t2, Ar, Az, An, Hn);
      xPart(t2 + 1, Br, Bz, Bn);
    }
    GRU_BARRIER();
    hPart(15, Br, Bz, Hn);
    gates(15, Br, Bz, Bn, Hn);           // publishes h(15) into hbuf[0]

    #pragma unroll
    for (int q=0; q<4; ++q){
      int n = tile*16 + grp*4 + q;
      if (n < N) hout[(size_t)n*128 + ch] = hreg[q];
    }

    // ---- epilogue: x = h @ lin^T, a_s/a_d dots ----
    GRU_BARRIER();
    {
      bf16x8 ha[4];
      const unsigned short* hb = hbuf[0];
      #pragma unroll
      for (int kt=0;kt<4;++kt){
        int chunk = (kt*4+grp) ^ col4;
        ha[kt] = *(const bf16x8*)(hb + col4*128 + chunk*8);
      }
      f32x4 acc = (f32x4)0.0f;
      #pragma unroll
      for (int kt=0; kt<4; ++kt)
        acc = __builtin_amdgcn_mfma_f32_16x16x32_bf16(ha[kt], Lf[kt], acc, 0,0,0);
      float ssq[4], ddq[4];
      #pragma unroll
      for (int q=0;q<4;++q){
        float xv = acc[q];
        int n = tile*16 + grp*4 + q;
        if (n < N) xbf[(size_t)n*128 + ch] = f2bf(xv);
        ssq[q] = xv * ats;
        ddq[q] = xv * atd;
      }
      #pragma unroll
      for (int m=1; m<16; m<<=1){
        #pragma unroll
        for (int q=0;q<4;++q){
          ssq[q] += __shfl_xor(ssq[q], m);
          ddq[q] += __shfl_xor(ddq[q], m);
        }
      }
      if (col4 == 0){
        #pragma unroll
        for (int q=0;q<4;++q){
          redS[w][grp*4+q] = ssq[q];
          redD[w][grp*4+q] = ddq[q];
        }
      }
      __syncthreads();
      if (w == 0 && lane < 16){
        float s = 0.f, d = 0.f;
        #pragma unroll
        for (int k=0;k<8;++k){ s += redS[k][lane]; d += redD[k][lane]; }
        int n = tile*16 + lane;
        if (n < N){ a_s[n] = s; a_d[n] = d; }
      }
      __syncthreads();   // redS/xbuf WAR guard before next tile's prologue
    }
  }
}

// ---------------- CSR aggregation: one wave per destination node, 8x unrolled ----------------
__global__ __launch_bounds__(256) void k_agg2(
    const int* __restrict__ off, const int* __restrict__ eid,
    const float* __restrict__ a_s, const float* __restrict__ a_d,
    const unsigned short* __restrict__ xbf, const float* __restrict__ bias,
    float* __restrict__ out2, int N)
{
  int d = blockIdx.x*4 + (threadIdx.x >> 6);
  if (d >= N) return;
  const int lane = threadIdx.x & 63;
  const unsigned* xw = (const unsigned*)xbf;   // 2 bf16 channels per uint
  const float ad_d = a_d[d];
  float a0 = a_s[d] + ad_d; a0 = a0 > 0.f ? a0 : 0.2f*a0;
  float w = __expf(a0);
  unsigned pv = xw[(size_t)d*64 + lane];
  float den  = w;
  float acc0 = w * bf2f((unsigned short)(pv & 0xffffu));
  float acc1 = w * bf2f((unsigned short)(pv >> 16));
  int i = off[d];
  const int i1 = off[d+1];
  for (; i + 7 < i1; i += 8){
    int   sj[8]; unsigned pj[8]; float bj[8];
    #pragma unroll
    for (int j=0;j<8;++j) sj[j] = eid[i+j];
    #pragma unroll
    for (int j=0;j<8;++j) pj[j] = xw[(size_t)sj[j]*64 + lane];
    #pragma unroll
    for (int j=0;j<8;++j){
      float b = a_s[sj[j]] + ad_d;
      bj[j] = b > 0.f ? b : 0.2f*b;
    }
    #pragma unroll
    for (int j=0;j<8;++j){
      float ww = __expf(bj[j]);
      den  += ww;
      acc0 += ww * bf2f((unsigned short)(pj[j] & 0xffffu));
      acc1 += ww * bf2f((unsigned short)(pj[j] >> 16));
    }
  }
  for (; i + 3 < i1; i += 4){
    int s0 = eid[i], s1 = eid[i+1], s2 = eid[i+2], s3 = eid[i+3];
    unsigned p0 = xw[(size_t)s0*64 + lane];
    unsigned p1 = xw[(size_t)s1*64 + lane];
    unsigned p2 = xw[(size_t)s2*64 + lane];
    unsigned p3 = xw[(size_t)s3*64 + lane];
    float b0 = a_s[s0] + ad_d, b1 = a_s[s1] + ad_d, b2 = a_s[s2] + ad_d, b3 = a_s[s3] + ad_d;
    b0 = b0 > 0.f ? b0 : 0.2f*b0;  b1 = b1 > 0.f ? b1 : 0.2f*b1;
    b2 = b2 > 0.f ? b2 : 0.2f*b2;  b3 = b3 > 0.f ? b3 : 0.2f*b3;
    float w0 = __expf(b0), w1 = __expf(b1), w2 = __expf(b2), w3 = __expf(b3);
    den += w0 + w1 + w2 + w3;
    acc0 += w0 * bf2f((unsigned short)(p0 & 0xffffu)) + w1 * bf2f((unsigned short)(p1 & 0xffffu))
          + w2 * bf2f((unsigned short)(p2 & 0xffffu)) + w3 * bf2f((unsigned short)(p3 & 0xffffu));
    acc1 += w0 * bf2f((unsigned short)(p0 >> 16)) + w1 * bf2f((unsigned short)(p1 >> 16))
          + w2 * bf2f((unsigned short)(p2 >> 16)) + w3 * bf2f((unsigned short)(p3 >> 16));
  }
  for (; i < i1; ++i){
    int s = eid[i];
    float a = a_s[s] + ad_d; a = a > 0.f ? a : 0.2f*a;
    float ww = __expf(a);
    unsigned pp = xw[(size_t)s*64 + lane];
    den  += ww;
    acc0 += ww * bf2f((unsigned short)(pp & 0xffffu));
    acc1 += ww * bf2f((unsigned short)(pp >> 16));
  }
  float inv = rcp_fast(den);
  float2 o;
  o.x = acc0*inv + bias[2*lane];
  o.y = acc1*inv + bias[2*lane+1];
  *(float2*)(out2 + (size_t)d*128 + 2*lane) = o;
}

extern "C" void kernel_launch(void* const* d_in, const int* in_sizes, int n_in,
                              void* d_out, int out_size, void* d_ws, size_t ws_size,
                              hipStream_t stream)
{
  const float* seq  = (const float*)d_in[0];
  const void*  ei   = d_in[1];
  const float* Wihf = (const float*)d_in[2];
  const float* Whhf = (const float*)d_in[3];
  const float* bih  = (const float*)d_in[4];
  const float* bhh  = (const float*)d_in[5];
  const float* linw = (const float*)d_in[6];
  const float* atts = (const float*)d_in[7];
  const float* attd = (const float*)d_in[8];
  const float* gbias= (const float*)d_in[9];

  const int N  = in_sizes[0] / (16*128);
  const int E  = in_sizes[1] / 2;
  const int nT = (N + 15) / 16;
  const int nB = (N + 1023) / 1024;

  char* ws = (char*)d_ws;
  size_t off_b = 0;
  auto alloc = [&](size_t bytes) -> char* {
    char* p = ws + off_b;
    off_b = (off_b + bytes + 255) & ~(size_t)255;
    return p;
  };
  unsigned short* Wih_sw = (unsigned short*)alloc(98304);
  unsigned short* Whh_sw = (unsigned short*)alloc(98304);
  unsigned short* lin_sw = (unsigned short*)alloc(32768);
  unsigned short* xbf    = (unsigned short*)alloc((size_t)N*128*2);
  float*    a_s    = (float*)   alloc((size_t)N*4);
  float*    a_d    = (float*)   alloc((size_t)N*4);
  unsigned* flag   = (unsigned*)alloc(64);
  int*      deg    = (int*)     alloc((size_t)N*4);
  int*      offs   = (int*)     alloc((size_t)(N+1)*4);
  int*      cur    = (int*)     alloc((size_t)N*4);
  int*      eid    = (int*)     alloc((size_t)E*4);
  int*      bsum   = (int*)     alloc((size_t)(nB+1)*4);
  int*      total  = (int*)     alloc(64);

  float* hout = (float*)d_out;
  float* out2 = hout + (size_t)N*128;

  k_prep   <<<448, 256, 0, stream>>>(Wihf, Whhf, linw, Wih_sw, Whh_sw, lin_sw);
  k_detzero<<<(N + 255)/256, 256, 0, stream>>>((const int*)ei, flag, deg, N);
  k_deg    <<<(E + 255)/256, 256, 0, stream>>>(ei, flag, deg, E);
  k_scanA  <<<nB, 256, 0, stream>>>(deg, offs, bsum, N);
  k_scanB  <<<1, 64, 0, stream>>>(bsum, total, nB);
  k_scanC  <<<(N + 255)/256, 256, 0, stream>>>(offs, bsum, total, cur, N);
  k_scatter<<<(E + 255)/256, 256, 0, stream>>>(ei, flag, cur, eid, E);

  int grid = nT < 512 ? nT : 512;
  k_gru_fused<<<grid, 512, 0, stream>>>(Wih_sw, Whh_sw, lin_sw, bih, bhh, atts, attd,
                                        seq, hout, xbf, a_s, a_d, nT, N);

  k_agg2<<<(N + 3)/4, 256, 0, stream>>>(offs, eid, a_s, a_d, xbf, gbias, out2, N);
}

// Round 16
// 180.266 us; speedup vs baseline: 1.3380x; 1.0457x over previous
//
#include <hip/hip_runtime.h>

typedef __bf16 bf16x8 __attribute__((ext_vector_type(8)));
typedef float  f32x4  __attribute__((ext_vector_type(4)));
union BF8 { unsigned short s[8]; bf16x8 v; };

#define LOG2E 1.44269504088896340736f

// LDS-only barrier (no vmcnt drain).
#define GRU_BARRIER() asm volatile("s_waitcnt lgkmcnt(0)\n\ts_barrier" ::: "memory")

__device__ __forceinline__ unsigned short f2bf(float x){
  unsigned u = __float_as_uint(x);
  u += 0x7fffu + ((u >> 16) & 1u);      // round-to-nearest-even
  return (unsigned short)(u >> 16);
}
__device__ __forceinline__ unsigned cvt_pk_bf16(float lo, float hi){
  unsigned r;
  asm("v_cvt_pk_bf16_f32 %0, %1, %2" : "=v"(r) : "v"(lo), "v"(hi));
  return r;
}
__device__ __forceinline__ float exp2_fast(float x){   // v_exp_f32 = 2^x
  float r; asm("v_exp_f32 %0, %1" : "=v"(r) : "v"(x)); return r;
}
__device__ __forceinline__ float rcp_fast(float x){    // v_rcp_f32
  float r; asm("v_rcp_f32 %0, %1" : "=v"(r) : "v"(x)); return r;
}
__device__ __forceinline__ float bf2f(unsigned short s){ return __uint_as_float(((unsigned)s) << 16); }

// ---------------- deg zero + edge dtype sniff (must precede k_prepdeg) ----------------
__global__ void k_detzero(const int* __restrict__ ei, unsigned* __restrict__ flag,
                          int* __restrict__ deg, int N){
  int tid = blockIdx.x*256 + threadIdx.x;
  if (tid < N) deg[tid] = 0;
  if (blockIdx.x == 0 && threadIdx.x < 64){
    int v = ei[2*threadIdx.x + 1];
    unsigned long long b = __ballot(v == 0);
    if (threadIdx.x == 0) flag[0] = (b == ~0ULL) ? 1u : 0u;
  }
}

// ---------------- prep (W -> bf16 pre-swizzled, pre-scaled) + deg histogram ----------------
__global__ void k_prepdeg(const float* __restrict__ Wihf, const float* __restrict__ Whhf,
                          const float* __restrict__ linw,
                          unsigned short* __restrict__ Wih_sw, unsigned short* __restrict__ Whh_sw,
                          unsigned short* __restrict__ lin_sw,
                          const void* __restrict__ ei, const unsigned* __restrict__ flag,
                          int* __restrict__ deg, int E)
{
  int tid = blockIdx.x*256 + threadIdx.x;
  if (tid < 49152){
    int row = tid >> 7, col = tid & 127;
    float sc = (row < 256) ? LOG2E : 2.0f*LOG2E;
    Wih_sw[row*128 + (((col>>3) ^ (row&7))<<3) + (col&7)] = f2bf(Wihf[tid]*sc);
  } else if (tid < 98304){
    int i = tid - 49152; int row = i >> 7, col = i & 127;
    float sc = (row < 256) ? LOG2E : 2.0f*LOG2E;
    Whh_sw[row*128 + (((col>>3) ^ (row&7))<<3) + (col&7)] = f2bf(Whhf[i]*sc);
  } else if (tid < 114688){
    int i = tid - 98304; int row = i >> 7, col = i & 127;
    lin_sw[row*128 + (((col>>3) ^ (row&7))<<3) + (col&7)] = f2bf(linw[i]);
  }
  if (tid < E){
    int d;
    if (flag[0]) d = (int)((const long long*)ei)[(size_t)E + tid];
    else         d = ((const int*)ei)[E + tid];
    atomicAdd(&deg[d], 1);
  }
}

// ---------------- scan level A: per-1024-block exclusive scan + block sums ----------------
__global__ __launch_bounds__(256) void k_scanA(const int* __restrict__ deg,
    int* __restrict__ off, int* __restrict__ bsum, int N){
  __shared__ int wsum[4];
  const int b = blockIdx.x, t = threadIdx.x;
  const int lane = t & 63, wv = t >> 6;
  const int base = b*1024 + t*4;
  int v[4]; int s = 0;
  #pragma unroll
  for (int j=0;j<4;++j){ v[j] = (base+j < N) ? deg[base+j] : 0; s += v[j]; }
  int inc = s;
  #pragma unroll
  for (int d2=1; d2<64; d2<<=1){ int u = __shfl_up(inc, d2); if (lane >= d2) inc += u; }
  if (lane == 63) wsum[wv] = inc;
  __syncthreads();
  int woff = 0;
  #pragma unroll
  for (int j=0;j<4;++j) if (j < wv) woff += wsum[j];
  int ex = woff + inc - s;
  #pragma unroll
  for (int j=0;j<4;++j){
    if (base+j < N) off[base+j] = ex;
    ex += v[j];
  }
  if (t == 255) bsum[b] = woff + inc;
}

// ---------------- scan level B+C merged: each block locally scans bsum (nB<=64) --------
__global__ __launch_bounds__(256) void k_scanC2(int* __restrict__ off,
    const int* __restrict__ bsum, int* __restrict__ cur, int N, int nB){
  __shared__ int incl[64];
  const int t = threadIdx.x;
  if (t < 64){
    int v = (t < nB) ? bsum[t] : 0;
    int inc = v;
    #pragma unroll
    for (int d2=1; d2<64; d2<<=1){ int u = __shfl_up(inc, d2); if (t >= d2) inc += u; }
    incl[t] = inc;
  }
  __syncthreads();
  int i = blockIdx.x*256 + t;
  if (i < N){
    int bidx = i >> 10;
    int add = bidx ? incl[bidx-1] : 0;
    int o = off[i] + add;
    off[i] = o; cur[i] = o;
  }
  if (i == 0) off[N] = incl[nB-1];
}

// scatter edge sources into CSR, reading edge_index directly (L3-hot 2nd pass)
__global__ void k_scatter(const void* __restrict__ ei, const unsigned* __restrict__ flag,
                          int* __restrict__ cur, int* __restrict__ eid, int E){
  int e = blockIdx.x*256 + threadIdx.x;
  if (e >= E) return;
  int s, d;
  if (flag[0]){
    const long long* p = (const long long*)ei;
    s = (int)p[e]; d = (int)p[(size_t)E + e];
  } else {
    const int* p = (const int*)ei;
    s = p[e]; d = p[E + e];
  }
  int pos = atomicAdd(&cur[d], 1);
  eid[pos] = s;
}

// ---------------- persistent fused GRU + GAT-linear epilogue ----------------
__global__ __launch_bounds__(512, 2) void k_gru_fused(
    const unsigned short* __restrict__ Wih_sw, const unsigned short* __restrict__ Whh_sw,
    const unsigned short* __restrict__ lin_sw,
    const float* __restrict__ bih, const float* __restrict__ bhh,
    const float* __restrict__ att_s, const float* __restrict__ att_d,
    const float* __restrict__ seq, float* __restrict__ hout,
    unsigned short* __restrict__ xbf, float* __restrict__ a_s, float* __restrict__ a_d,
    int nT, int N)
{
  __shared__ unsigned short xbuf[2][16*256];   // [slot][node][s(2 steps)][ch swz]
  __shared__ unsigned short hbuf[2][16*128];   // [buf][node][ch swz]
  __shared__ float redS[8][16], redD[8][16];
  const int tid  = threadIdx.x;
  const int lane = tid & 63, w = tid >> 6;     // w = channel chunk 0..7
  const int col4 = lane & 15, grp = lane >> 4;
  const int ch   = 16*w + col4;                // this lane's output channel

  bf16x8 Wf[6][4], Lf[4];
  #pragma unroll
  for (int s6=0; s6<6; ++s6){
    const unsigned short* Wp = (s6 < 3) ? Wih_sw : Whh_sw;
    int row = (s6 % 3)*128 + ch;
    #pragma unroll
    for (int kt=0; kt<4; ++kt)
      Wf[s6][kt] = *(const bf16x8*)(Wp + row*128 + (((kt*4+grp) ^ (row&7))<<3));
  }
  #pragma unroll
  for (int kt=0; kt<4; ++kt)
    Lf[kt] = *(const bf16x8*)(lin_sw + ch*128 + (((kt*4+grp) ^ (ch&7))<<3));
  const float brz_r = (bih[ch]       + bhh[ch])       * LOG2E;
  const float brz_z = (bih[128 + ch] + bhh[128 + ch]) * LOG2E;
  const float b_xn  = bih[256 + ch] * (2.0f*LOG2E);
  const float b_hn  = bhh[256 + ch] * (2.0f*LOG2E);
  const float ats   = att_s[ch];
  const float atd   = att_d[ch];

  float hreg[4];
  f32x4 sv[2];
  auto stageIssue = [&](int tile, int p){     // load pair p (steps 2p,2p+1)
    #pragma unroll
    for (int rr=0; rr<2; ++rr){
      int nrow = tile*16 + 2*w + rr; if (nrow >= N) nrow = N-1;
      sv[rr] = *(const f32x4*)(seq + ((size_t)nrow*16 + 2*p)*128 + lane*4);
    }
  };
  auto stageWrite = [&](int p){
    const int s  = lane >> 5;
    const int c0 = (lane & 31) * 4;
    #pragma unroll
    for (int rr=0; rr<2; ++rr){
      int node = 2*w + rr;
      int chunk = (c0 >> 3) ^ node;
      uint2 pk;
      pk.x = cvt_pk_bf16(sv[rr][0], sv[rr][1]);
      pk.y = cvt_pk_bf16(sv[rr][2], sv[rr][3]);
      *(uint2*)(&xbuf[p & 1][node*256 + s*128 + chunk*8 + (c0 & 7)]) = pk;
    }
  };

  auto xPart = [&](int t, f32x4& nr, f32x4& nz, f32x4& nn){
    bf16x8 xa[4];
    const unsigned short* xb = xbuf[(t>>1)&1] + col4*256 + (t&1)*128;
    #pragma unroll
    for (int kt=0;kt<4;++kt){
      int chunk = (kt*4+grp) ^ col4;
      xa[kt] = *(const bf16x8*)(xb + chunk*8);
    }
    nr = (f32x4){brz_r, brz_r, brz_r, brz_r};
    nz = (f32x4){brz_z, brz_z, brz_z, brz_z};
    nn = (f32x4){b_xn,  b_xn,  b_xn,  b_xn };
    #pragma unroll
    for (int kt=0; kt<4; ++kt){
      nr = __builtin_amdgcn_mfma_f32_16x16x32_bf16(xa[kt], Wf[0][kt], nr, 0,0,0);
      nz = __builtin_amdgcn_mfma_f32_16x16x32_bf16(xa[kt], Wf[1][kt], nz, 0,0,0);
      nn = __builtin_amdgcn_mfma_f32_16x16x32_bf16(xa[kt], Wf[2][kt], nn, 0,0,0);
    }
  };
  auto hPart = [&](int t, f32x4& cr, f32x4& cz, f32x4& chn){
    bf16x8 ha[4];
    const unsigned short* hb = hbuf[t&1];
    #pragma unroll
    for (int kt=0;kt<4;++kt){
      int chunk = (kt*4+grp) ^ col4;
      ha[kt] = *(const bf16x8*)(hb + col4*128 + chunk*8);
    }
    chn = (f32x4){b_hn, b_hn, b_hn, b_hn};
    #pragma unroll
    for (int kt=0; kt<4; ++kt){
      cr  = __builtin_amdgcn_mfma_f32_16x16x32_bf16(ha[kt], Wf[3][kt], cr , 0,0,0);
      cz  = __builtin_amdgcn_mfma_f32_16x16x32_bf16(ha[kt], Wf[4][kt], cz , 0,0,0);
      chn = __builtin_amdgcn_mfma_f32_16x16x32_bf16(ha[kt], Wf[5][kt], chn, 0,0,0);
    }
  };
  auto gates = [&](int t, const f32x4& cr, const f32x4& cz, const f32x4& cn, const f32x4& chn){
    unsigned short* hbw = hbuf[(t+1)&1];
    #pragma unroll
    for (int q=0; q<4; q+=2){
      float r0 = rcp_fast(1.0f + exp2_fast(-cr[q]));
      float z0 = rcp_fast(1.0f + exp2_fast(-cz[q]));
      float n0 = 1.0f - 2.0f*rcp_fast(exp2_fast(cn[q]   + r0*chn[q])   + 1.0f);
      float h0 = n0 + z0*(hreg[q]   - n0); hreg[q]   = h0;
      float r1 = rcp_fast(1.0f + exp2_fast(-cr[q+1]));
      float z1 = rcp_fast(1.0f + exp2_fast(-cz[q+1]));
      float n1 = 1.0f - 2.0f*rcp_fast(exp2_fast(cn[q+1] + r1*chn[q+1]) + 1.0f);
      float h1 = n1 + z1*(hreg[q+1] - n1); hreg[q+1] = h1;
      unsigned pk = cvt_pk_bf16(h0, h1);
      int nd0 = grp*4 + q, nd1 = nd0 + 1;
      int c0 = ((ch>>3) ^ nd0), c1 = ((ch>>3) ^ nd1);
      hbw[nd0*128 + c0*8 + (ch&7)] = (unsigned short)pk;
      hbw[nd1*128 + c1*8 + (ch&7)] = (unsigned short)(pk >> 16);
    }
  };

  for (int tile = blockIdx.x; tile < nT; tile += gridDim.x){
    #pragma unroll
    for (int q=0;q<4;++q) hreg[q] = 0.f;

    stageIssue(tile, 0); stageWrite(0);
    stageIssue(tile, 1); stageWrite(1);
    stageIssue(tile, 2);
    __syncthreads();

    f32x4 Ar, Az, An, Br, Bz, Bn, Hn;
    xPart(0, Ar, Az, An);
    Hn = (f32x4){b_hn, b_hn, b_hn, b_hn};    // h(-1) = 0
    gates(0, Ar, Az, An, Hn);
    xPart(1, Br, Bz, Bn);

    for (int tp = 0; tp < 7; ++tp){
      const int t1 = 2*tp + 1, t2 = 2*tp + 2;
      GRU_BARRIER();
      if (tp <= 5) stageWrite(tp + 2);
      if (tp <= 4) stageIssue(tile, tp + 3);
      hPart(t1, Br, Bz, Hn);
      gates(t1, Br, Bz, Bn, Hn);
      xPart(t2, Ar, Az, An);
      GRU_BARRIER();
      hPart(t2, Ar, Az, Hn);
      gates(t2, Ar, Az, An, Hn);
      xPart(t2 + 1, Br, Bz, Bn);
    }
    GRU_BARRIER();
    hPart(15, Br, Bz, Hn);
    gates(15, Br, Bz, Bn, Hn);           // publishes h(15) into hbuf[0]

    #pragma unroll
    for (int q=0; q<4; ++q){
      int n = tile*16 + grp*4 + q;
      if (n < N) hout[(size_t)n*128 + ch] = hreg[q];
    }

    // ---- epilogue: x = h @ lin^T, a_s/a_d dots ----
    GRU_BARRIER();
    {
      bf16x8 ha[4];
      const unsigned short* hb = hbuf[0];
      #pragma unroll
      for (int kt=0;kt<4;++kt){
        int chunk = (kt*4+grp) ^ col4;
        ha[kt] = *(const bf16x8*)(hb + col4*128 + chunk*8);
      }
      f32x4 acc = (f32x4)0.0f;
      #pragma unroll
      for (int kt=0; kt<4; ++kt)
        acc = __builtin_amdgcn_mfma_f32_16x16x32_bf16(ha[kt], Lf[kt], acc, 0,0,0);
      float ssq[4], ddq[4];
      #pragma unroll
      for (int q=0;q<4;++q){
        float xv = acc[q];
        int n = tile*16 + grp*4 + q;
        if (n < N) xbf[(size_t)n*128 + ch] = f2bf(xv);
        ssq[q] = xv * ats;
        ddq[q] = xv * atd;
      }
      #pragma unroll
      for (int m=1; m<16; m<<=1){
        #pragma unroll
        for (int q=0;q<4;++q){
          ssq[q] += __shfl_xor(ssq[q], m);
          ddq[q] += __shfl_xor(ddq[q], m);
        }
      }
      if (col4 == 0){
        #pragma unroll
        for (int q=0;q<4;++q){
          redS[w][grp*4+q] = ssq[q];
          redD[w][grp*4+q] = ddq[q];
        }
      }
      __syncthreads();
      if (w == 0 && lane < 16){
        float s = 0.f, d = 0.f;
        #pragma unroll
        for (int k=0;k<8;++k){ s += redS[k][lane]; d += redD[k][lane]; }
        int n = tile*16 + lane;
        if (n < N){ a_s[n] = s; a_d[n] = d; }
      }
      __syncthreads();   // redS/xbuf WAR guard before next tile's prologue
    }
  }
}

// ---------------- CSR aggregation: one wave per destination node, 8x unrolled ----------------
__global__ __launch_bounds__(256) void k_agg2(
    const int* __restrict__ off, const int* __restrict__ eid,
    const float* __restrict__ a_s, const float* __restrict__ a_d,
    const unsigned short* __restrict__ xbf, const float* __restrict__ bias,
    float* __restrict__ out2, int N)
{
  int d = blockIdx.x*4 + (threadIdx.x >> 6);
  if (d >= N) return;
  const int lane = threadIdx.x & 63;
  const unsigned* xw = (const unsigned*)xbf;   // 2 bf16 channels per uint
  const float ad_d = a_d[d];
  float a0 = a_s[d] + ad_d; a0 = a0 > 0.f ? a0 : 0.2f*a0;
  float w = __expf(a0);
  unsigned pv = xw[(size_t)d*64 + lane];
  float den  = w;
  float acc0 = w * bf2f((unsigned short)(pv & 0xffffu));
  float acc1 = w * bf2f((unsigned short)(pv >> 16));
  int i = off[d];
  const int i1 = off[d+1];
  for (; i + 7 < i1; i += 8){
    int   sj[8]; unsigned pj[8]; float bj[8];
    #pragma unroll
    for (int j=0;j<8;++j) sj[j] = eid[i+j];
    #pragma unroll
    for (int j=0;j<8;++j) pj[j] = xw[(size_t)sj[j]*64 + lane];
    #pragma unroll
    for (int j=0;j<8;++j){
      float b = a_s[sj[j]] + ad_d;
      bj[j] = b > 0.f ? b : 0.2f*b;
    }
    #pragma unroll
    for (int j=0;j<8;++j){
      float ww = __expf(bj[j]);
      den  += ww;
      acc0 += ww * bf2f((unsigned short)(pj[j] & 0xffffu));
      acc1 += ww * bf2f((unsigned short)(pj[j] >> 16));
    }
  }
  for (; i + 3 < i1; i += 4){
    int s0 = eid[i], s1 = eid[i+1], s2 = eid[i+2], s3 = eid[i+3];
    unsigned p0 = xw[(size_t)s0*64 + lane];
    unsigned p1 = xw[(size_t)s1*64 + lane];
    unsigned p2 = xw[(size_t)s2*64 + lane];
    unsigned p3 = xw[(size_t)s3*64 + lane];
    float b0 = a_s[s0] + ad_d, b1 = a_s[s1] + ad_d, b2 = a_s[s2] + ad_d, b3 = a_s[s3] + ad_d;
    b0 = b0 > 0.f ? b0 : 0.2f*b0;  b1 = b1 > 0.f ? b1 : 0.2f*b1;
    b2 = b2 > 0.f ? b2 : 0.2f*b2;  b3 = b3 > 0.f ? b3 : 0.2f*b3;
    float w0 = __expf(b0), w1 = __expf(b1), w2 = __expf(b2), w3 = __expf(b3);
    den += w0 + w1 + w2 + w3;
    acc0 += w0 * bf2f((unsigned short)(p0 & 0xffffu)) + w1 * bf2f((unsigned short)(p1 & 0xffffu))
          + w2 * bf2f((unsigned short)(p2 & 0xffffu)) + w3 * bf2f((unsigned short)(p3 & 0xffffu));
    acc1 += w0 * bf2f((unsigned short)(p0 >> 16)) + w1 * bf2f((unsigned short)(p1 >> 16))
          + w2 * bf2f((unsigned short)(p2 >> 16)) + w3 * bf2f((unsigned short)(p3 >> 16));
  }
  for (; i < i1; ++i){
    int s = eid[i];
    float a = a_s[s] + ad_d; a = a > 0.f ? a : 0.2f*a;
    float ww = __expf(a);
    unsigned pp = xw[(size_t)s*64 + lane];
    den  += ww;
    acc0 += ww * bf2f((unsigned short)(pp & 0xffffu));
    acc1 += ww * bf2f((unsigned short)(pp >> 16));
  }
  float inv = rcp_fast(den);
  float2 o;
  o.x = acc0*inv + bias[2*lane];
  o.y = acc1*inv + bias[2*lane+1];
  *(float2*)(out2 + (size_t)d*128 + 2*lane) = o;
}

extern "C" void kernel_launch(void* const* d_in, const int* in_sizes, int n_in,
                              void* d_out, int out_size, void* d_ws, size_t ws_size,
                              hipStream_t stream)
{
  const float* seq  = (const float*)d_in[0];
  const void*  ei   = d_in[1];
  const float* Wihf = (const float*)d_in[2];
  const float* Whhf = (const float*)d_in[3];
  const float* bih  = (const float*)d_in[4];
  const float* bhh  = (const float*)d_in[5];
  const float* linw = (const float*)d_in[6];
  const float* atts = (const float*)d_in[7];
  const float* attd = (const float*)d_in[8];
  const float* gbias= (const float*)d_in[9];

  const int N  = in_sizes[0] / (16*128);
  const int E  = in_sizes[1] / 2;
  const int nT = (N + 15) / 16;
  const int nB = (N + 1023) / 1024;

  char* ws = (char*)d_ws;
  size_t off_b = 0;
  auto alloc = [&](size_t bytes) -> char* {
    char* p = ws + off_b;
    off_b = (off_b + bytes + 255) & ~(size_t)255;
    return p;
  };
  unsigned short* Wih_sw = (unsigned short*)alloc(98304);
  unsigned short* Whh_sw = (unsigned short*)alloc(98304);
  unsigned short* lin_sw = (unsigned short*)alloc(32768);
  unsigned short* xbf    = (unsigned short*)alloc((size_t)N*128*2);
  float*    a_s    = (float*)   alloc((size_t)N*4);
  float*    a_d    = (float*)   alloc((size_t)N*4);
  unsigned* flag   = (unsigned*)alloc(64);
  int*      deg    = (int*)     alloc((size_t)N*4);
  int*      offs   = (int*)     alloc((size_t)(N+1)*4);
  int*      cur    = (int*)     alloc((size_t)N*4);
  int*      eid    = (int*)     alloc((size_t)E*4);
  int*      bsum   = (int*)     alloc((size_t)(nB+1)*4);

  float* hout = (float*)d_out;
  float* out2 = hout + (size_t)N*128;

  k_detzero<<<(N + 255)/256, 256, 0, stream>>>((const int*)ei, flag, deg, N);
  int prepGrid = (E > 114688 ? E : 114688);
  k_prepdeg<<<(prepGrid + 255)/256, 256, 0, stream>>>(Wihf, Whhf, linw, Wih_sw, Whh_sw,
                                                      lin_sw, ei, flag, deg, E);
  k_scanA  <<<nB, 256, 0, stream>>>(deg, offs, bsum, N);
  k_scanC2 <<<(N + 255)/256, 256, 0, stream>>>(offs, bsum, cur, N, nB);
  k_scatter<<<(E + 255)/256, 256, 0, stream>>>(ei, flag, cur, eid, E);

  int grid = nT < 512 ? nT : 512;
  k_gru_fused<<<grid, 512, 0, stream>>>(Wih_sw, Whh_sw, lin_sw, bih, bhh, atts, attd,
                                        seq, hout, xbf, a_s, a_d, nT, N);

  k_agg2<<<(N + 3)/4, 256, 0, stream>>>(offs, eid, a_s, a_d, xbf, gbias, out2, N);
}